// Round 3
// baseline (613.332 us; speedup 1.0000x reference)
//
#include <hip/hip_runtime.h>

// ---------------------------------------------------------------------------
// GCNConv + ReLU, exploiting linearity (aggregate-then-transform):
//   deg[c]  = 1 + sum_{e: col[e]=c} w[e]
//   dinv    = rsqrt(deg)
//   agg[c]  = dinv[c]^2 * x[c] + sum_{e: col[e]=c} (dinv[row]*w*dinv[c]) * x[row]
//   out     = relu(agg @ W + b)
// agg is written into d_out (gathers read only the immutable input x), then the
// GEMM runs in-place on d_out (each block's 128-row tile is block-private).
// Workspace: CSR only (~14.4 MB).
// NOTE: edge_index arrives as int32 per harness contract ("integer -> const int*").
// ---------------------------------------------------------------------------

__global__ void init_kernel(float* __restrict__ deg, int* __restrict__ counts,
                            int* __restrict__ cursor, int n) {
    int i = blockIdx.x * blockDim.x + threadIdx.x;
    if (i < n) {
        deg[i] = 1.0f;   // self-loop weight
        counts[i] = 0;
        cursor[i] = 0;
    }
}

__global__ void edge_deg_hist(const int* __restrict__ col,
                              const float* __restrict__ w,
                              float* __restrict__ deg, int* __restrict__ counts, int E) {
    int e = blockIdx.x * blockDim.x + threadIdx.x;
    if (e < E) {
        int c = col[e];
        atomicAdd(&deg[c], w[e]);
        atomicAdd(&counts[c], 1);
    }
}

__global__ void dinv_kernel(float* __restrict__ deg, int n) {
    int i = blockIdx.x * blockDim.x + threadIdx.x;
    if (i < n) {
        float d = deg[i];
        deg[i] = (d > 0.0f) ? rsqrtf(d) : 0.0f;
    }
}

// Single-block exclusive scan over counts[0..n) -> offs[0..n], offs[n] = total.
__global__ void scan_kernel(const int* __restrict__ counts, int* __restrict__ offs,
                            int n, int total) {
    __shared__ int lds[1024];
    int tid = threadIdx.x;
    int chunk = (n + 1023) >> 10;
    int base = tid * chunk;
    int end = base + chunk;
    if (end > n) end = n;

    int s = 0;
    for (int i = base; i < end; ++i) s += counts[i];
    lds[tid] = s;
    __syncthreads();

    for (int off = 1; off < 1024; off <<= 1) {
        int v = (tid >= off) ? lds[tid - off] : 0;
        __syncthreads();
        lds[tid] += v;
        __syncthreads();
    }

    int ex = (tid > 0) ? lds[tid - 1] : 0;
    for (int i = base; i < end; ++i) {
        offs[i] = ex;
        ex += counts[i];
    }
    if (tid == 0) offs[n] = total;
}

__global__ void scatter_kernel(const int* __restrict__ row,
                               const int* __restrict__ col,
                               const float* __restrict__ w,
                               const float* __restrict__ dinv,
                               const int* __restrict__ offs,
                               int* __restrict__ cursor,
                               int* __restrict__ srcRow, float* __restrict__ nwS, int E) {
    int e = blockIdx.x * blockDim.x + threadIdx.x;
    if (e < E) {
        int r = row[e];
        int c = col[e];
        float nw = dinv[r] * w[e] * dinv[c];
        int p = offs[c] + atomicAdd(&cursor[c], 1);
        srcRow[p] = r;
        nwS[p] = nw;
    }
}

// One wave per node: lane owns channels {2*lane, 2*lane+1}. Gathers x rows.
__launch_bounds__(256)
__global__ void agg_kernel(const float* __restrict__ x, const float* __restrict__ dinv,
                           const int* __restrict__ offs, const int* __restrict__ srcRow,
                           const float* __restrict__ nwS,
                           float* __restrict__ aggOut, int n) {
    int wid = (blockIdx.x * blockDim.x + threadIdx.x) >> 6;
    int lane = threadIdx.x & 63;
    if (wid >= n) return;

    float di = dinv[wid];
    float2 xi = *reinterpret_cast<const float2*>(&x[(size_t)wid * 128 + lane * 2]);
    float sw = di * di;   // self-loop weight: dinv^2 * 1.0
    float2 acc;
    acc.x = sw * xi.x;
    acc.y = sw * xi.y;

    int s = offs[wid];
    int e = offs[wid + 1];
    int j = s;
    if (j < e) {
        int r = srcRow[j];
        float wn = nwS[j];
        for (; j + 1 < e; ++j) {
            int rn = srcRow[j + 1];       // prefetch next edge meta
            float wnn = nwS[j + 1];
            float2 v = *reinterpret_cast<const float2*>(&x[(size_t)r * 128 + lane * 2]);
            acc.x += wn * v.x;
            acc.y += wn * v.y;
            r = rn;
            wn = wnn;
        }
        float2 v = *reinterpret_cast<const float2*>(&x[(size_t)r * 128 + lane * 2]);
        acc.x += wn * v.x;
        acc.y += wn * v.y;
    }

    *reinterpret_cast<float2*>(&aggOut[(size_t)wid * 128 + lane * 2]) = acc;
}

// out = relu(in @ W + b), in-place safe (in == out): each block stages its own
// 128-row tile into LDS before computing/writing. 8x8 register tile per thread.
__launch_bounds__(256)
__global__ void gemm_inplace(const float* __restrict__ in, const float* __restrict__ W,
                             const float* __restrict__ bias,
                             float* __restrict__ out, int n) {
    __shared__ float xs[128 * 128];  // 64 KiB
    __shared__ float wl[128 * 128];  // 64 KiB
    const int tid = threadIdx.x;
    const int rbase = blockIdx.x * 128;

    #pragma unroll
    for (int i = 0; i < 16; ++i) {
        int f = tid + i * 256;          // float4 index 0..4095
        int row = f >> 5;               // 0..127
        int c4 = f & 31;                // 0..31
        float4 v = make_float4(0.f, 0.f, 0.f, 0.f);
        if (rbase + row < n)
            v = reinterpret_cast<const float4*>(in)[(size_t)(rbase + row) * 32 + c4];
        reinterpret_cast<float4*>(xs)[row * 32 + c4] = v;
        reinterpret_cast<float4*>(wl)[f] = reinterpret_cast<const float4*>(W)[f];
    }
    __syncthreads();

    const int tx = tid & 15;
    const int ty = tid >> 4;
    const int c0 = tx * 8;
    const int r0 = ty * 8;

    float acc[8][8];
    #pragma unroll
    for (int i = 0; i < 8; ++i)
        #pragma unroll
        for (int j = 0; j < 8; ++j) acc[i][j] = 0.f;

    for (int k = 0; k < 128; k += 4) {
        float4 a[8];
        float4 b4[4][2];
        #pragma unroll
        for (int i = 0; i < 8; ++i)
            a[i] = *reinterpret_cast<const float4*>(&xs[(r0 + i) * 128 + k]);
        #pragma unroll
        for (int kk = 0; kk < 4; ++kk) {
            b4[kk][0] = *reinterpret_cast<const float4*>(&wl[(k + kk) * 128 + c0]);
            b4[kk][1] = *reinterpret_cast<const float4*>(&wl[(k + kk) * 128 + c0 + 4]);
        }
        #pragma unroll
        for (int kk = 0; kk < 4; ++kk) {
            #pragma unroll
            for (int i = 0; i < 8; ++i) {
                float av = reinterpret_cast<const float*>(&a[i])[kk];
                acc[i][0] += av * b4[kk][0].x;
                acc[i][1] += av * b4[kk][0].y;
                acc[i][2] += av * b4[kk][0].z;
                acc[i][3] += av * b4[kk][0].w;
                acc[i][4] += av * b4[kk][1].x;
                acc[i][5] += av * b4[kk][1].y;
                acc[i][6] += av * b4[kk][1].z;
                acc[i][7] += av * b4[kk][1].w;
            }
        }
    }

    float bb[8];
    #pragma unroll
    for (int j = 0; j < 8; ++j) bb[j] = bias[c0 + j];

    #pragma unroll
    for (int i = 0; i < 8; ++i) {
        int row = rbase + r0 + i;
        if (row < n) {
            float4 o0, o1;
            o0.x = fmaxf(acc[i][0] + bb[0], 0.f);
            o0.y = fmaxf(acc[i][1] + bb[1], 0.f);
            o0.z = fmaxf(acc[i][2] + bb[2], 0.f);
            o0.w = fmaxf(acc[i][3] + bb[3], 0.f);
            o1.x = fmaxf(acc[i][4] + bb[4], 0.f);
            o1.y = fmaxf(acc[i][5] + bb[5], 0.f);
            o1.z = fmaxf(acc[i][6] + bb[6], 0.f);
            o1.w = fmaxf(acc[i][7] + bb[7], 0.f);
            reinterpret_cast<float4*>(out)[(size_t)row * 32 + (c0 >> 2)] = o0;
            reinterpret_cast<float4*>(out)[(size_t)row * 32 + (c0 >> 2) + 1] = o1;
        }
    }
}

extern "C" void kernel_launch(void* const* d_in, const int* in_sizes, int n_in,
                              void* d_out, int out_size, void* d_ws, size_t ws_size,
                              hipStream_t stream) {
    const float* x = (const float*)d_in[0];
    const int* ei = (const int*)d_in[1];        // harness contract: integer -> int32
    const float* w = (const float*)d_in[2];
    const float* W = (const float*)d_in[3];
    const float* b = (const float*)d_in[4];
    float* out = (float*)d_out;

    const int N = in_sizes[0] / 128;
    const int E = in_sizes[2];
    const int* row = ei;       // source
    const int* col = ei + E;   // target

    // Workspace partition (~14.4 MB total)
    char* ws = (char*)d_ws;
    float* deg = (float*)ws;     ws += (size_t)N * sizeof(float);        // becomes dinv in place
    int* counts = (int*)ws;      ws += (size_t)N * sizeof(int);
    int* cursor = (int*)ws;      ws += (size_t)N * sizeof(int);
    int* offs = (int*)ws;        ws += (size_t)(N + 1) * sizeof(int);
    int* srcRow = (int*)ws;      ws += (size_t)E * sizeof(int);          // 6.4 MB
    float* nwS = (float*)ws;     ws += (size_t)E * sizeof(float);        // 6.4 MB

    const int B = 256;

    init_kernel<<<(N + B - 1) / B, B, 0, stream>>>(deg, counts, cursor, N);
    edge_deg_hist<<<(E + B - 1) / B, B, 0, stream>>>(col, w, deg, counts, E);
    dinv_kernel<<<(N + B - 1) / B, B, 0, stream>>>(deg, N);
    scan_kernel<<<1, 1024, 0, stream>>>(counts, offs, N, E);
    scatter_kernel<<<(E + B - 1) / B, B, 0, stream>>>(row, col, w, deg, offs, cursor,
                                                      srcRow, nwS, E);
    // Aggregate x into d_out (4 nodes/waves per 256-thread block)
    agg_kernel<<<(N + 3) / 4, 256, 0, stream>>>(x, deg, offs, srcRow, nwS, out, N);
    // out = relu(out @ W + b), in-place
    gemm_inplace<<<(N + 127) / 128, 256, 0, stream>>>(out, W, b, out, N);
}

// Round 4
// 463.078 us; speedup vs baseline: 1.3245x; 1.3245x over previous
//
#include <hip/hip_runtime.h>

// ---------------------------------------------------------------------------
// GCNConv + ReLU, aggregate-then-transform (GCN is linear before the GEMM):
//   deg[c]  = 1 + sum_{e: col[e]=c} w[e]
//   dinv    = rsqrt(deg)
//   agg[c]  = dinv[c]^2 * x[c] + sum_{e: col[e]=c} (dinv[row]*w*dinv[c]) * x[row]
//   out     = relu(agg @ W + b)
// agg lands in d_out (reads only immutable x), GEMM runs in-place on d_out.
// R3: replaced single-block scan (161 us, 1 CU busy) with hierarchical
// 3-dispatch scan (~20 us); dinv fused into scan1.
// ---------------------------------------------------------------------------

__global__ void init_kernel(float* __restrict__ deg, int* __restrict__ counts,
                            int* __restrict__ cursor, int n) {
    int i = blockIdx.x * blockDim.x + threadIdx.x;
    if (i < n) {
        deg[i] = 1.0f;   // self-loop weight
        counts[i] = 0;
        cursor[i] = 0;
    }
}

__global__ void edge_deg_hist(const int* __restrict__ col,
                              const float* __restrict__ w,
                              float* __restrict__ deg, int* __restrict__ counts, int E) {
    int e = blockIdx.x * blockDim.x + threadIdx.x;
    if (e < E) {
        int c = col[e];
        atomicAdd(&deg[c], w[e]);
        atomicAdd(&counts[c], 1);
    }
}

// Block-local exclusive scan of 1024-element chunks of counts -> offs (partial),
// block totals -> blockSums. Fused: deg -> rsqrt(deg) in place (same range).
__launch_bounds__(256)
__global__ void scan1_kernel(const int* __restrict__ counts, float* __restrict__ deg,
                             int* __restrict__ offs, int* __restrict__ blockSums, int n) {
    __shared__ int waveSums[4];
    const int tid = threadIdx.x;
    const int lane = tid & 63;
    const int wv = tid >> 6;
    const int base = blockIdx.x * 1024 + tid * 4;

    int c0 = 0, c1 = 0, c2 = 0, c3 = 0;
    if (base + 3 < n) {
        int4 c = *reinterpret_cast<const int4*>(&counts[base]);
        c0 = c.x; c1 = c.y; c2 = c.z; c3 = c.w;
    } else {
        if (base     < n) c0 = counts[base];
        if (base + 1 < n) c1 = counts[base + 1];
        if (base + 2 < n) c2 = counts[base + 2];
        // base+3 < n handled above
    }
    int s1 = c0 + c1, s2 = s1 + c2, s3 = s2 + c3;

    // wave-inclusive scan of per-thread sums
    int incl = s3;
    #pragma unroll
    for (int off = 1; off < 64; off <<= 1) {
        int v = __shfl_up(incl, off);
        if (lane >= off) incl += v;
    }
    if (lane == 63) waveSums[wv] = incl;
    __syncthreads();
    if (tid == 0) {
        int a = 0;
        #pragma unroll
        for (int i = 0; i < 4; ++i) { int t = waveSums[i]; waveSums[i] = a; a += t; }
        blockSums[blockIdx.x] = a;
    }
    __syncthreads();

    int ex = waveSums[wv] + (incl - s3);   // exclusive prefix for this thread's chunk
    if (base + 3 < n) {
        int4 o;
        o.x = ex; o.y = ex + c0; o.z = ex + s1; o.w = ex + s2;
        *reinterpret_cast<int4*>(&offs[base]) = o;
    } else {
        if (base     < n) offs[base]     = ex;
        if (base + 1 < n) offs[base + 1] = ex + c0;
        if (base + 2 < n) offs[base + 2] = ex + s1;
    }

    // fused dinv on the same 4 indices
    if (base + 3 < n) {
        float4 d = *reinterpret_cast<const float4*>(&deg[base]);
        d.x = rsqrtf(d.x); d.y = rsqrtf(d.y); d.z = rsqrtf(d.z); d.w = rsqrtf(d.w);
        *reinterpret_cast<float4*>(&deg[base]) = d;
    } else {
        if (base     < n) deg[base]     = rsqrtf(deg[base]);
        if (base + 1 < n) deg[base + 1] = rsqrtf(deg[base + 1]);
        if (base + 2 < n) deg[base + 2] = rsqrtf(deg[base + 2]);
    }
}

// Exclusive scan of blockSums (nb <= 1024), single small block.
__global__ void scan2_kernel(int* __restrict__ blockSums, int nb) {
    __shared__ int lds[1024];
    int tid = threadIdx.x;
    if (tid < nb) lds[tid] = blockSums[tid];
    __syncthreads();
    if (tid == 0) {
        int a = 0;
        for (int i = 0; i < nb; ++i) { int t = lds[i]; lds[i] = a; a += t; }
    }
    __syncthreads();
    if (tid < nb) blockSums[tid] = lds[tid];
}

// offs[i] += blockSums[i>>10]; also offs[n] = total.
__launch_bounds__(256)
__global__ void scan3_kernel(int* __restrict__ offs, const int* __restrict__ blockSums,
                             int n, int total) {
    int i = (blockIdx.x * 256 + threadIdx.x) * 4;
    int bs = blockSums[blockIdx.x];    // 256 threads x int4 = 1024 elems = scan1 chunk
    if (i + 3 < n) {
        int4 v = *reinterpret_cast<const int4*>(&offs[i]);
        v.x += bs; v.y += bs; v.z += bs; v.w += bs;
        *reinterpret_cast<int4*>(&offs[i]) = v;
    } else {
        if (i     < n) offs[i]     += bs;
        if (i + 1 < n) offs[i + 1] += bs;
        if (i + 2 < n) offs[i + 2] += bs;
    }
    if (blockIdx.x == 0 && threadIdx.x == 0) offs[n] = total;
}

__global__ void scatter_kernel(const int* __restrict__ row,
                               const int* __restrict__ col,
                               const float* __restrict__ w,
                               const float* __restrict__ dinv,
                               const int* __restrict__ offs,
                               int* __restrict__ cursor,
                               int* __restrict__ srcRow, float* __restrict__ nwS, int E) {
    int e = blockIdx.x * blockDim.x + threadIdx.x;
    if (e < E) {
        int r = row[e];
        int c = col[e];
        float nw = dinv[r] * w[e] * dinv[c];
        int p = offs[c] + atomicAdd(&cursor[c], 1);
        srcRow[p] = r;
        nwS[p] = nw;
    }
}

// One wave per node: lane owns channels {2*lane, 2*lane+1}. Gathers x rows.
__launch_bounds__(256)
__global__ void agg_kernel(const float* __restrict__ x, const float* __restrict__ dinv,
                           const int* __restrict__ offs, const int* __restrict__ srcRow,
                           const float* __restrict__ nwS,
                           float* __restrict__ aggOut, int n) {
    int wid = (blockIdx.x * blockDim.x + threadIdx.x) >> 6;
    int lane = threadIdx.x & 63;
    if (wid >= n) return;

    float di = dinv[wid];
    float2 xi = *reinterpret_cast<const float2*>(&x[(size_t)wid * 128 + lane * 2]);
    float sw = di * di;   // self-loop: dinv^2 * 1.0
    float2 acc;
    acc.x = sw * xi.x;
    acc.y = sw * xi.y;

    int s = offs[wid];
    int e = offs[wid + 1];
    int j = s;
    if (j < e) {
        int r = srcRow[j];
        float wn = nwS[j];
        for (; j + 1 < e; ++j) {
            int rn = srcRow[j + 1];       // prefetch next edge meta
            float wnn = nwS[j + 1];
            float2 v = *reinterpret_cast<const float2*>(&x[(size_t)r * 128 + lane * 2]);
            acc.x += wn * v.x;
            acc.y += wn * v.y;
            r = rn;
            wn = wnn;
        }
        float2 v = *reinterpret_cast<const float2*>(&x[(size_t)r * 128 + lane * 2]);
        acc.x += wn * v.x;
        acc.y += wn * v.y;
    }

    *reinterpret_cast<float2*>(&aggOut[(size_t)wid * 128 + lane * 2]) = acc;
}

// out = relu(in @ W + b), in-place safe: block stages its 128-row tile in LDS.
__launch_bounds__(256)
__global__ void gemm_inplace(const float* __restrict__ in, const float* __restrict__ W,
                             const float* __restrict__ bias,
                             float* __restrict__ out, int n) {
    __shared__ float xs[128 * 128];  // 64 KiB
    __shared__ float wl[128 * 128];  // 64 KiB
    const int tid = threadIdx.x;
    const int rbase = blockIdx.x * 128;

    #pragma unroll
    for (int i = 0; i < 16; ++i) {
        int f = tid + i * 256;          // float4 index 0..4095
        int row = f >> 5;
        int c4 = f & 31;
        float4 v = make_float4(0.f, 0.f, 0.f, 0.f);
        if (rbase + row < n)
            v = reinterpret_cast<const float4*>(in)[(size_t)(rbase + row) * 32 + c4];
        reinterpret_cast<float4*>(xs)[row * 32 + c4] = v;
        reinterpret_cast<float4*>(wl)[f] = reinterpret_cast<const float4*>(W)[f];
    }
    __syncthreads();

    const int tx = tid & 15;
    const int ty = tid >> 4;
    const int c0 = tx * 8;
    const int r0 = ty * 8;

    float acc[8][8];
    #pragma unroll
    for (int i = 0; i < 8; ++i)
        #pragma unroll
        for (int j = 0; j < 8; ++j) acc[i][j] = 0.f;

    for (int k = 0; k < 128; k += 4) {
        float4 a[8];
        float4 b4[4][2];
        #pragma unroll
        for (int i = 0; i < 8; ++i)
            a[i] = *reinterpret_cast<const float4*>(&xs[(r0 + i) * 128 + k]);
        #pragma unroll
        for (int kk = 0; kk < 4; ++kk) {
            b4[kk][0] = *reinterpret_cast<const float4*>(&wl[(k + kk) * 128 + c0]);
            b4[kk][1] = *reinterpret_cast<const float4*>(&wl[(k + kk) * 128 + c0 + 4]);
        }
        #pragma unroll
        for (int kk = 0; kk < 4; ++kk) {
            #pragma unroll
            for (int i = 0; i < 8; ++i) {
                float av = reinterpret_cast<const float*>(&a[i])[kk];
                acc[i][0] += av * b4[kk][0].x;
                acc[i][1] += av * b4[kk][0].y;
                acc[i][2] += av * b4[kk][0].z;
                acc[i][3] += av * b4[kk][0].w;
                acc[i][4] += av * b4[kk][1].x;
                acc[i][5] += av * b4[kk][1].y;
                acc[i][6] += av * b4[kk][1].z;
                acc[i][7] += av * b4[kk][1].w;
            }
        }
    }

    float bb[8];
    #pragma unroll
    for (int j = 0; j < 8; ++j) bb[j] = bias[c0 + j];

    #pragma unroll
    for (int i = 0; i < 8; ++i) {
        int row = rbase + r0 + i;
        if (row < n) {
            float4 o0, o1;
            o0.x = fmaxf(acc[i][0] + bb[0], 0.f);
            o0.y = fmaxf(acc[i][1] + bb[1], 0.f);
            o0.z = fmaxf(acc[i][2] + bb[2], 0.f);
            o0.w = fmaxf(acc[i][3] + bb[3], 0.f);
            o1.x = fmaxf(acc[i][4] + bb[4], 0.f);
            o1.y = fmaxf(acc[i][5] + bb[5], 0.f);
            o1.z = fmaxf(acc[i][6] + bb[6], 0.f);
            o1.w = fmaxf(acc[i][7] + bb[7], 0.f);
            reinterpret_cast<float4*>(out)[(size_t)row * 32 + (c0 >> 2)] = o0;
            reinterpret_cast<float4*>(out)[(size_t)row * 32 + (c0 >> 2) + 1] = o1;
        }
    }
}

extern "C" void kernel_launch(void* const* d_in, const int* in_sizes, int n_in,
                              void* d_out, int out_size, void* d_ws, size_t ws_size,
                              hipStream_t stream) {
    const float* x = (const float*)d_in[0];
    const int* ei = (const int*)d_in[1];        // harness: integer -> int32
    const float* w = (const float*)d_in[2];
    const float* W = (const float*)d_in[3];
    const float* b = (const float*)d_in[4];
    float* out = (float*)d_out;

    const int N = in_sizes[0] / 128;
    const int E = in_sizes[2];
    const int* row = ei;       // source
    const int* col = ei + E;   // target

    const int nScan = (N + 1023) / 1024;   // 98 for N=100000 (<= 1024 required)

    // Workspace partition (~14.5 MB total)
    char* ws = (char*)d_ws;
    float* deg = (float*)ws;     ws += (size_t)N * sizeof(float);        // becomes dinv
    int* counts = (int*)ws;      ws += (size_t)N * sizeof(int);
    int* cursor = (int*)ws;      ws += (size_t)N * sizeof(int);
    int* offs = (int*)ws;        ws += (size_t)(N + 1) * sizeof(int);
    int* blockSums = (int*)ws;   ws += (size_t)1024 * sizeof(int);
    int* srcRow = (int*)ws;      ws += (size_t)E * sizeof(int);          // 6.4 MB
    float* nwS = (float*)ws;     ws += (size_t)E * sizeof(float);        // 6.4 MB

    const int B = 256;

    init_kernel<<<(N + B - 1) / B, B, 0, stream>>>(deg, counts, cursor, N);
    edge_deg_hist<<<(E + B - 1) / B, B, 0, stream>>>(col, w, deg, counts, E);
    scan1_kernel<<<nScan, 256, 0, stream>>>(counts, deg, offs, blockSums, N);
    scan2_kernel<<<1, 1024, 0, stream>>>(blockSums, nScan);
    scan3_kernel<<<nScan, 256, 0, stream>>>(offs, blockSums, N, E);
    scatter_kernel<<<(E + B - 1) / B, B, 0, stream>>>(row, col, w, deg, offs, cursor,
                                                      srcRow, nwS, E);
    // Aggregate x into d_out (4 nodes/waves per 256-thread block)
    agg_kernel<<<(N + 3) / 4, 256, 0, stream>>>(x, deg, offs, srcRow, nwS, out, N);
    // out = relu(out @ W + b), in-place
    gemm_inplace<<<(N + 127) / 128, 256, 0, stream>>>(out, W, b, out, N);
}

// Round 5
// 405.517 us; speedup vs baseline: 1.5125x; 1.1419x over previous
//
#include <hip/hip_runtime.h>

// ---------------------------------------------------------------------------
// GCNConv + ReLU, aggregate-then-transform (GCN is linear before the GEMM):
//   deg[c]  = 1 + sum_{e: col[e]=c} w[e]
//   dinv    = rsqrt(deg)
//   agg[c]  = dinv[c]^2 * x[c] + sum_{e: col[e]=c} (dinv[row]*w*dinv[c]) * x[row]
//   out     = relu(agg @ W + b)
// R4: atomics are write-through to the coherence point (~32B/atomic, measured
// WRITE_SIZE == 32B * #atomics). So: one packed 64-bit atomic carries BOTH the
// edge count (hi32) and the weighted degree (lo32, 8.24 fixed point, init 1.0)
// -> half the hist atomics. CSR entries interleaved as int2 -> one 8B store.
// ---------------------------------------------------------------------------

static __device__ __forceinline__ float fix2float(unsigned int v) {
    return (float)v * 5.9604644775390625e-8f;   // * 2^-24
}

__global__ void init_kernel(unsigned long long* __restrict__ packed,
                            int* __restrict__ cursor, int n) {
    int i = blockIdx.x * blockDim.x + threadIdx.x;
    if (i < n) {
        packed[i] = (unsigned long long)(1u << 24);  // deg = 1.0 (self-loop), count = 0
        cursor[i] = 0;
    }
}

__global__ void edge_hist(const int* __restrict__ col,
                          const float* __restrict__ w,
                          unsigned long long* __restrict__ packed, int E) {
    int e = blockIdx.x * blockDim.x + threadIdx.x;
    if (e < E) {
        unsigned int fx = (unsigned int)(w[e] * 16777216.0f);  // w in [0,1): < 2^24
        atomicAdd(&packed[col[e]], (1ULL << 32) | (unsigned long long)fx);
    }
}

// Block-local exclusive scan of 1024-element chunks: counts = packed.hi -> offs
// (partial) + blockSums; fused dinv[i] = rsqrt(packed.lo * 2^-24).
__launch_bounds__(256)
__global__ void scan1_kernel(const unsigned long long* __restrict__ packed,
                             float* __restrict__ dinv,
                             int* __restrict__ offs, int* __restrict__ blockSums, int n) {
    __shared__ int waveSums[4];
    const int tid = threadIdx.x;
    const int lane = tid & 63;
    const int wv = tid >> 6;
    const int base = blockIdx.x * 1024 + tid * 4;

    int c0 = 0, c1 = 0, c2 = 0, c3 = 0;
    if (base + 3 < n) {
        unsigned long long p0 = packed[base];
        unsigned long long p1 = packed[base + 1];
        unsigned long long p2 = packed[base + 2];
        unsigned long long p3 = packed[base + 3];
        c0 = (int)(p0 >> 32); c1 = (int)(p1 >> 32);
        c2 = (int)(p2 >> 32); c3 = (int)(p3 >> 32);
        float4 d;
        d.x = rsqrtf(fix2float((unsigned int)p0));
        d.y = rsqrtf(fix2float((unsigned int)p1));
        d.z = rsqrtf(fix2float((unsigned int)p2));
        d.w = rsqrtf(fix2float((unsigned int)p3));
        *reinterpret_cast<float4*>(&dinv[base]) = d;
    } else {
        for (int t = 0; t < 4; ++t) {
            if (base + t < n) {
                unsigned long long p = packed[base + t];
                int cv = (int)(p >> 32);
                if (t == 0) c0 = cv; else if (t == 1) c1 = cv;
                else if (t == 2) c2 = cv;  else c3 = cv;
                dinv[base + t] = rsqrtf(fix2float((unsigned int)p));
            }
        }
    }
    int s1 = c0 + c1, s2 = s1 + c2, s3 = s2 + c3;

    // wave-inclusive scan of per-thread sums
    int incl = s3;
    #pragma unroll
    for (int off = 1; off < 64; off <<= 1) {
        int v = __shfl_up(incl, off);
        if (lane >= off) incl += v;
    }
    if (lane == 63) waveSums[wv] = incl;
    __syncthreads();
    if (tid == 0) {
        int a = 0;
        #pragma unroll
        for (int i = 0; i < 4; ++i) { int t = waveSums[i]; waveSums[i] = a; a += t; }
        blockSums[blockIdx.x] = a;
    }
    __syncthreads();

    int ex = waveSums[wv] + (incl - s3);
    if (base + 3 < n) {
        int4 o;
        o.x = ex; o.y = ex + c0; o.z = ex + s1; o.w = ex + s2;
        *reinterpret_cast<int4*>(&offs[base]) = o;
    } else {
        if (base     < n) offs[base]     = ex;
        if (base + 1 < n) offs[base + 1] = ex + c0;
        if (base + 2 < n) offs[base + 2] = ex + s1;
    }
}

// Exclusive scan of blockSums (nb <= 1024), single small block.
__global__ void scan2_kernel(int* __restrict__ blockSums, int nb) {
    __shared__ int lds[1024];
    int tid = threadIdx.x;
    if (tid < nb) lds[tid] = blockSums[tid];
    __syncthreads();
    if (tid == 0) {
        int a = 0;
        for (int i = 0; i < nb; ++i) { int t = lds[i]; lds[i] = a; a += t; }
    }
    __syncthreads();
    if (tid < nb) blockSums[tid] = lds[tid];
}

// offs[i] += blockSums[i>>10]; also offs[n] = total.
__launch_bounds__(256)
__global__ void scan3_kernel(int* __restrict__ offs, const int* __restrict__ blockSums,
                             int n, int total) {
    int i = (blockIdx.x * 256 + threadIdx.x) * 4;
    int bs = blockSums[blockIdx.x];
    if (i + 3 < n) {
        int4 v = *reinterpret_cast<const int4*>(&offs[i]);
        v.x += bs; v.y += bs; v.z += bs; v.w += bs;
        *reinterpret_cast<int4*>(&offs[i]) = v;
    } else {
        if (i     < n) offs[i]     += bs;
        if (i + 1 < n) offs[i + 1] += bs;
        if (i + 2 < n) offs[i + 2] += bs;
    }
    if (blockIdx.x == 0 && threadIdx.x == 0) offs[n] = total;
}

__global__ void scatter_kernel(const int* __restrict__ row,
                               const int* __restrict__ col,
                               const float* __restrict__ w,
                               const float* __restrict__ dinv,
                               const int* __restrict__ offs,
                               int* __restrict__ cursor,
                               int2* __restrict__ csr, int E) {
    int e = blockIdx.x * blockDim.x + threadIdx.x;
    if (e < E) {
        int r = row[e];
        int c = col[e];
        float nw = dinv[r] * w[e] * dinv[c];
        int p = offs[c] + atomicAdd(&cursor[c], 1);
        csr[p] = make_int2(r, __float_as_int(nw));   // one 8B store
    }
}

// One wave per node: lane owns channels {2*lane, 2*lane+1}. Gathers x rows.
__launch_bounds__(256)
__global__ void agg_kernel(const float* __restrict__ x, const float* __restrict__ dinv,
                           const int* __restrict__ offs, const int2* __restrict__ csr,
                           float* __restrict__ aggOut, int n) {
    int wid = (blockIdx.x * blockDim.x + threadIdx.x) >> 6;
    int lane = threadIdx.x & 63;
    if (wid >= n) return;

    float di = dinv[wid];
    float2 xi = *reinterpret_cast<const float2*>(&x[(size_t)wid * 128 + lane * 2]);
    float sw = di * di;   // self-loop: dinv^2 * 1.0
    float2 acc;
    acc.x = sw * xi.x;
    acc.y = sw * xi.y;

    int s = offs[wid];
    int e = offs[wid + 1];
    int j = s;
    if (j < e) {
        int2 m = csr[j];
        for (; j + 1 < e; ++j) {
            int2 mn = csr[j + 1];          // prefetch next edge meta
            float wn = __int_as_float(m.y);
            float2 v = *reinterpret_cast<const float2*>(&x[(size_t)m.x * 128 + lane * 2]);
            acc.x += wn * v.x;
            acc.y += wn * v.y;
            m = mn;
        }
        float wn = __int_as_float(m.y);
        float2 v = *reinterpret_cast<const float2*>(&x[(size_t)m.x * 128 + lane * 2]);
        acc.x += wn * v.x;
        acc.y += wn * v.y;
    }

    *reinterpret_cast<float2*>(&aggOut[(size_t)wid * 128 + lane * 2]) = acc;
}

// out = relu(in @ W + b), in-place safe: block stages its 128-row tile in LDS.
__launch_bounds__(256)
__global__ void gemm_inplace(const float* __restrict__ in, const float* __restrict__ W,
                             const float* __restrict__ bias,
                             float* __restrict__ out, int n) {
    __shared__ float xs[128 * 128];  // 64 KiB
    __shared__ float wl[128 * 128];  // 64 KiB
    const int tid = threadIdx.x;
    const int rbase = blockIdx.x * 128;

    #pragma unroll
    for (int i = 0; i < 16; ++i) {
        int f = tid + i * 256;
        int row = f >> 5;
        int c4 = f & 31;
        float4 v = make_float4(0.f, 0.f, 0.f, 0.f);
        if (rbase + row < n)
            v = reinterpret_cast<const float4*>(in)[(size_t)(rbase + row) * 32 + c4];
        reinterpret_cast<float4*>(xs)[row * 32 + c4] = v;
        reinterpret_cast<float4*>(wl)[f] = reinterpret_cast<const float4*>(W)[f];
    }
    __syncthreads();

    const int tx = tid & 15;
    const int ty = tid >> 4;
    const int c0 = tx * 8;
    const int r0 = ty * 8;

    float acc[8][8];
    #pragma unroll
    for (int i = 0; i < 8; ++i)
        #pragma unroll
        for (int j = 0; j < 8; ++j) acc[i][j] = 0.f;

    for (int k = 0; k < 128; k += 4) {
        float4 a[8];
        float4 b4[4][2];
        #pragma unroll
        for (int i = 0; i < 8; ++i)
            a[i] = *reinterpret_cast<const float4*>(&xs[(r0 + i) * 128 + k]);
        #pragma unroll
        for (int kk = 0; kk < 4; ++kk) {
            b4[kk][0] = *reinterpret_cast<const float4*>(&wl[(k + kk) * 128 + c0]);
            b4[kk][1] = *reinterpret_cast<const float4*>(&wl[(k + kk) * 128 + c0 + 4]);
        }
        #pragma unroll
        for (int kk = 0; kk < 4; ++kk) {
            #pragma unroll
            for (int i = 0; i < 8; ++i) {
                float av = reinterpret_cast<const float*>(&a[i])[kk];
                acc[i][0] += av * b4[kk][0].x;
                acc[i][1] += av * b4[kk][0].y;
                acc[i][2] += av * b4[kk][0].z;
                acc[i][3] += av * b4[kk][0].w;
                acc[i][4] += av * b4[kk][1].x;
                acc[i][5] += av * b4[kk][1].y;
                acc[i][6] += av * b4[kk][1].z;
                acc[i][7] += av * b4[kk][1].w;
            }
        }
    }

    float bb[8];
    #pragma unroll
    for (int j = 0; j < 8; ++j) bb[j] = bias[c0 + j];

    #pragma unroll
    for (int i = 0; i < 8; ++i) {
        int row = rbase + r0 + i;
        if (row < n) {
            float4 o0, o1;
            o0.x = fmaxf(acc[i][0] + bb[0], 0.f);
            o0.y = fmaxf(acc[i][1] + bb[1], 0.f);
            o0.z = fmaxf(acc[i][2] + bb[2], 0.f);
            o0.w = fmaxf(acc[i][3] + bb[3], 0.f);
            o1.x = fmaxf(acc[i][4] + bb[4], 0.f);
            o1.y = fmaxf(acc[i][5] + bb[5], 0.f);
            o1.z = fmaxf(acc[i][6] + bb[6], 0.f);
            o1.w = fmaxf(acc[i][7] + bb[7], 0.f);
            reinterpret_cast<float4*>(out)[(size_t)row * 32 + (c0 >> 2)] = o0;
            reinterpret_cast<float4*>(out)[(size_t)row * 32 + (c0 >> 2) + 1] = o1;
        }
    }
}

extern "C" void kernel_launch(void* const* d_in, const int* in_sizes, int n_in,
                              void* d_out, int out_size, void* d_ws, size_t ws_size,
                              hipStream_t stream) {
    const float* x = (const float*)d_in[0];
    const int* ei = (const int*)d_in[1];        // harness: integer -> int32
    const float* w = (const float*)d_in[2];
    const float* W = (const float*)d_in[3];
    const float* b = (const float*)d_in[4];
    float* out = (float*)d_out;

    const int N = in_sizes[0] / 128;
    const int E = in_sizes[2];
    const int* row = ei;       // source
    const int* col = ei + E;   // target

    const int nScan = (N + 1023) / 1024;   // 98 for N=100000

    // Workspace partition (~15 MB total)
    char* ws = (char*)d_ws;
    unsigned long long* packed = (unsigned long long*)ws;
                                 ws += (size_t)N * sizeof(unsigned long long);
    float* dinv = (float*)ws;    ws += (size_t)N * sizeof(float);
    int* cursor = (int*)ws;      ws += (size_t)N * sizeof(int);
    int* offs = (int*)ws;        ws += (size_t)(N + 1) * sizeof(int);
    int* blockSums = (int*)ws;   ws += (size_t)1024 * sizeof(int);
    int2* csr = (int2*)ws;       ws += (size_t)E * sizeof(int2);      // 12.8 MB

    const int B = 256;

    init_kernel<<<(N + B - 1) / B, B, 0, stream>>>(packed, cursor, N);
    edge_hist<<<(E + B - 1) / B, B, 0, stream>>>(col, w, packed, E);
    scan1_kernel<<<nScan, 256, 0, stream>>>(packed, dinv, offs, blockSums, N);
    scan2_kernel<<<1, 1024, 0, stream>>>(blockSums, nScan);
    scan3_kernel<<<nScan, 256, 0, stream>>>(offs, blockSums, N, E);
    scatter_kernel<<<(E + B - 1) / B, B, 0, stream>>>(row, col, w, dinv, offs, cursor,
                                                      csr, E);
    // Aggregate x into d_out (4 nodes/waves per 256-thread block)
    agg_kernel<<<(N + 3) / 4, 256, 0, stream>>>(x, dinv, offs, csr, out, N);
    // out = relu(out @ W + b), in-place
    gemm_inplace<<<(N + 127) / 128, 256, 0, stream>>>(out, W, b, out, N);
}

// Round 6
// 395.817 us; speedup vs baseline: 1.5495x; 1.0245x over previous
//
#include <hip/hip_runtime.h>

// ---------------------------------------------------------------------------
// GCNConv + ReLU, aggregate-then-transform (GCN is linear before the GEMM):
//   deg[c]  = 1 + sum_{e: col[e]=c} w[e]
//   dinv    = rsqrt(deg)
//   agg[c]  = dinv[c]^2 * x[c] + sum_{e: col[e]=c} (dinv[row]*w*dinv[c]) * x[row]
//   out     = relu(agg @ W + b)
// R4: packed 64-bit hist atomic (count hi32 | 8.24 fixed-point deg lo32).
// R5: agg is gather-BW-bound (FETCH 405 MB, 54% L2 hit on random 512B rows).
//     Gather bf16 instead: x converted once to bf16 (fused into the hist
//     kernel's idle read pipe), agg reads 256B/row, accumulates fp32.
// ---------------------------------------------------------------------------

static __device__ __forceinline__ float fix2float(unsigned int v) {
    return (float)v * 5.9604644775390625e-8f;   // * 2^-24
}

// fp32 bits -> bf16 (RNE), packed pair (lo element in low 16 bits)
static __device__ __forceinline__ unsigned int pack_bf2(unsigned int lo, unsigned int hi) {
    unsigned int l = (lo + 0x7FFFu + ((lo >> 16) & 1u)) >> 16;
    unsigned int h = (hi + 0x7FFFu + ((hi >> 16) & 1u)) >> 16;
    return l | (h << 16);
}

static __device__ __forceinline__ float2 bf2_to_f2(unsigned int u) {
    union { unsigned int i; float f; } a, b;
    a.i = u << 16;
    b.i = u & 0xFFFF0000u;
    return make_float2(a.f, b.f);
}

__global__ void init_kernel(unsigned long long* __restrict__ packed,
                            int* __restrict__ cursor, int n) {
    int i = blockIdx.x * blockDim.x + threadIdx.x;
    if (i < n) {
        packed[i] = (unsigned long long)(1u << 24);  // deg = 1.0 (self-loop), count = 0
        cursor[i] = 0;
    }
}

// Fused: per-edge degree histogram (atomic pipe) + x -> bf16 conversion
// (read/write pipe). Thread t handles edge t and x elements [16t, 16t+16)... no:
// [8t, 8t+8) — exactly covers N*128 when E*8 >= N*128.
__global__ void hist_cvt_kernel(const int* __restrict__ col,
                                const float* __restrict__ w,
                                unsigned long long* __restrict__ packed,
                                const float* __restrict__ x,
                                unsigned int* __restrict__ xbf2,  // N*64 packed pairs
                                int E, int nx8) {
    int t = blockIdx.x * blockDim.x + threadIdx.x;
    if (t < nx8) {
        const uint4* xin = reinterpret_cast<const uint4*>(x);
        uint4 a = xin[t * 2];
        uint4 b = xin[t * 2 + 1];
        uint4 o;
        o.x = pack_bf2(a.x, a.y);
        o.y = pack_bf2(a.z, a.w);
        o.z = pack_bf2(b.x, b.y);
        o.w = pack_bf2(b.z, b.w);
        reinterpret_cast<uint4*>(xbf2)[t] = o;
    }
    if (t < E) {
        unsigned int fx = (unsigned int)(w[t] * 16777216.0f);  // w in [0,1): < 2^24
        atomicAdd(&packed[col[t]], (1ULL << 32) | (unsigned long long)fx);
    }
}

// Plain hist (fallback when ws can't hold xbf2).
__global__ void edge_hist(const int* __restrict__ col,
                          const float* __restrict__ w,
                          unsigned long long* __restrict__ packed, int E) {
    int e = blockIdx.x * blockDim.x + threadIdx.x;
    if (e < E) {
        unsigned int fx = (unsigned int)(w[e] * 16777216.0f);
        atomicAdd(&packed[col[e]], (1ULL << 32) | (unsigned long long)fx);
    }
}

// Block-local exclusive scan of 1024-element chunks: counts = packed.hi -> offs
// (partial) + blockSums; fused dinv[i] = rsqrt(packed.lo * 2^-24).
__launch_bounds__(256)
__global__ void scan1_kernel(const unsigned long long* __restrict__ packed,
                             float* __restrict__ dinv,
                             int* __restrict__ offs, int* __restrict__ blockSums, int n) {
    __shared__ int waveSums[4];
    const int tid = threadIdx.x;
    const int lane = tid & 63;
    const int wv = tid >> 6;
    const int base = blockIdx.x * 1024 + tid * 4;

    int c0 = 0, c1 = 0, c2 = 0, c3 = 0;
    if (base + 3 < n) {
        unsigned long long p0 = packed[base];
        unsigned long long p1 = packed[base + 1];
        unsigned long long p2 = packed[base + 2];
        unsigned long long p3 = packed[base + 3];
        c0 = (int)(p0 >> 32); c1 = (int)(p1 >> 32);
        c2 = (int)(p2 >> 32); c3 = (int)(p3 >> 32);
        float4 d;
        d.x = rsqrtf(fix2float((unsigned int)p0));
        d.y = rsqrtf(fix2float((unsigned int)p1));
        d.z = rsqrtf(fix2float((unsigned int)p2));
        d.w = rsqrtf(fix2float((unsigned int)p3));
        *reinterpret_cast<float4*>(&dinv[base]) = d;
    } else {
        for (int t = 0; t < 4; ++t) {
            if (base + t < n) {
                unsigned long long p = packed[base + t];
                int cv = (int)(p >> 32);
                if (t == 0) c0 = cv; else if (t == 1) c1 = cv;
                else if (t == 2) c2 = cv;  else c3 = cv;
                dinv[base + t] = rsqrtf(fix2float((unsigned int)p));
            }
        }
    }
    int s1 = c0 + c1, s2 = s1 + c2, s3 = s2 + c3;

    int incl = s3;
    #pragma unroll
    for (int off = 1; off < 64; off <<= 1) {
        int v = __shfl_up(incl, off);
        if (lane >= off) incl += v;
    }
    if (lane == 63) waveSums[wv] = incl;
    __syncthreads();
    if (tid == 0) {
        int a = 0;
        #pragma unroll
        for (int i = 0; i < 4; ++i) { int t = waveSums[i]; waveSums[i] = a; a += t; }
        blockSums[blockIdx.x] = a;
    }
    __syncthreads();

    int ex = waveSums[wv] + (incl - s3);
    if (base + 3 < n) {
        int4 o;
        o.x = ex; o.y = ex + c0; o.z = ex + s1; o.w = ex + s2;
        *reinterpret_cast<int4*>(&offs[base]) = o;
    } else {
        if (base     < n) offs[base]     = ex;
        if (base + 1 < n) offs[base + 1] = ex + c0;
        if (base + 2 < n) offs[base + 2] = ex + s1;
    }
}

__global__ void scan2_kernel(int* __restrict__ blockSums, int nb) {
    __shared__ int lds[1024];
    int tid = threadIdx.x;
    if (tid < nb) lds[tid] = blockSums[tid];
    __syncthreads();
    if (tid == 0) {
        int a = 0;
        for (int i = 0; i < nb; ++i) { int t = lds[i]; lds[i] = a; a += t; }
    }
    __syncthreads();
    if (tid < nb) blockSums[tid] = lds[tid];
}

__launch_bounds__(256)
__global__ void scan3_kernel(int* __restrict__ offs, const int* __restrict__ blockSums,
                             int n, int total) {
    int i = (blockIdx.x * 256 + threadIdx.x) * 4;
    int bs = blockSums[blockIdx.x];
    if (i + 3 < n) {
        int4 v = *reinterpret_cast<const int4*>(&offs[i]);
        v.x += bs; v.y += bs; v.z += bs; v.w += bs;
        *reinterpret_cast<int4*>(&offs[i]) = v;
    } else {
        if (i     < n) offs[i]     += bs;
        if (i + 1 < n) offs[i + 1] += bs;
        if (i + 2 < n) offs[i + 2] += bs;
    }
    if (blockIdx.x == 0 && threadIdx.x == 0) offs[n] = total;
}

__global__ void scatter_kernel(const int* __restrict__ row,
                               const int* __restrict__ col,
                               const float* __restrict__ w,
                               const float* __restrict__ dinv,
                               const int* __restrict__ offs,
                               int* __restrict__ cursor,
                               int2* __restrict__ csr, int E) {
    int e = blockIdx.x * blockDim.x + threadIdx.x;
    if (e < E) {
        int r = row[e];
        int c = col[e];
        float nw = dinv[r] * w[e] * dinv[c];
        int p = offs[c] + atomicAdd(&cursor[c], 1);
        csr[p] = make_int2(r, __float_as_int(nw));   // one 8B store
    }
}

// One wave per node, bf16 gathers: lane owns channels {2*lane, 2*lane+1} as one
// packed bf16x2 dword. fp32 accumulate.
__launch_bounds__(256)
__global__ void agg_kernel_bf16(const unsigned int* __restrict__ xbf2,
                                const float* __restrict__ dinv,
                                const int* __restrict__ offs, const int2* __restrict__ csr,
                                float* __restrict__ aggOut, int n) {
    int wid = (blockIdx.x * blockDim.x + threadIdx.x) >> 6;
    int lane = threadIdx.x & 63;
    if (wid >= n) return;

    float di = dinv[wid];
    float2 xi = bf2_to_f2(xbf2[(size_t)wid * 64 + lane]);
    float sw = di * di;   // self-loop: dinv^2 * 1.0
    float2 acc;
    acc.x = sw * xi.x;
    acc.y = sw * xi.y;

    int s = offs[wid];
    int e = offs[wid + 1];
    int j = s;
    if (j < e) {
        int2 m = csr[j];
        for (; j + 1 < e; ++j) {
            int2 mn = csr[j + 1];          // prefetch next edge meta
            float wn = __int_as_float(m.y);
            float2 v = bf2_to_f2(xbf2[(size_t)m.x * 64 + lane]);
            acc.x += wn * v.x;
            acc.y += wn * v.y;
            m = mn;
        }
        float wn = __int_as_float(m.y);
        float2 v = bf2_to_f2(xbf2[(size_t)m.x * 64 + lane]);
        acc.x += wn * v.x;
        acc.y += wn * v.y;
    }

    *reinterpret_cast<float2*>(&aggOut[(size_t)wid * 128 + lane * 2]) = acc;
}

// fp32 fallback (ws too small for xbf2)
__launch_bounds__(256)
__global__ void agg_kernel_f32(const float* __restrict__ x, const float* __restrict__ dinv,
                               const int* __restrict__ offs, const int2* __restrict__ csr,
                               float* __restrict__ aggOut, int n) {
    int wid = (blockIdx.x * blockDim.x + threadIdx.x) >> 6;
    int lane = threadIdx.x & 63;
    if (wid >= n) return;

    float di = dinv[wid];
    float2 xi = *reinterpret_cast<const float2*>(&x[(size_t)wid * 128 + lane * 2]);
    float sw = di * di;
    float2 acc;
    acc.x = sw * xi.x;
    acc.y = sw * xi.y;

    int s = offs[wid];
    int e = offs[wid + 1];
    int j = s;
    if (j < e) {
        int2 m = csr[j];
        for (; j + 1 < e; ++j) {
            int2 mn = csr[j + 1];
            float wn = __int_as_float(m.y);
            float2 v = *reinterpret_cast<const float2*>(&x[(size_t)m.x * 128 + lane * 2]);
            acc.x += wn * v.x;
            acc.y += wn * v.y;
            m = mn;
        }
        float wn = __int_as_float(m.y);
        float2 v = *reinterpret_cast<const float2*>(&x[(size_t)m.x * 128 + lane * 2]);
        acc.x += wn * v.x;
        acc.y += wn * v.y;
    }

    *reinterpret_cast<float2*>(&aggOut[(size_t)wid * 128 + lane * 2]) = acc;
}

// out = relu(in @ W + b), in-place safe: block stages its 128-row tile in LDS.
__launch_bounds__(256)
__global__ void gemm_inplace(const float* __restrict__ in, const float* __restrict__ W,
                             const float* __restrict__ bias,
                             float* __restrict__ out, int n) {
    __shared__ float xs[128 * 128];  // 64 KiB
    __shared__ float wl[128 * 128];  // 64 KiB
    const int tid = threadIdx.x;
    const int rbase = blockIdx.x * 128;

    #pragma unroll
    for (int i = 0; i < 16; ++i) {
        int f = tid + i * 256;
        int row = f >> 5;
        int c4 = f & 31;
        float4 v = make_float4(0.f, 0.f, 0.f, 0.f);
        if (rbase + row < n)
            v = reinterpret_cast<const float4*>(in)[(size_t)(rbase + row) * 32 + c4];
        reinterpret_cast<float4*>(xs)[row * 32 + c4] = v;
        reinterpret_cast<float4*>(wl)[f] = reinterpret_cast<const float4*>(W)[f];
    }
    __syncthreads();

    const int tx = tid & 15;
    const int ty = tid >> 4;
    const int c0 = tx * 8;
    const int r0 = ty * 8;

    float acc[8][8];
    #pragma unroll
    for (int i = 0; i < 8; ++i)
        #pragma unroll
        for (int j = 0; j < 8; ++j) acc[i][j] = 0.f;

    for (int k = 0; k < 128; k += 4) {
        float4 a[8];
        float4 b4[4][2];
        #pragma unroll
        for (int i = 0; i < 8; ++i)
            a[i] = *reinterpret_cast<const float4*>(&xs[(r0 + i) * 128 + k]);
        #pragma unroll
        for (int kk = 0; kk < 4; ++kk) {
            b4[kk][0] = *reinterpret_cast<const float4*>(&wl[(k + kk) * 128 + c0]);
            b4[kk][1] = *reinterpret_cast<const float4*>(&wl[(k + kk) * 128 + c0 + 4]);
        }
        #pragma unroll
        for (int kk = 0; kk < 4; ++kk) {
            #pragma unroll
            for (int i = 0; i < 8; ++i) {
                float av = reinterpret_cast<const float*>(&a[i])[kk];
                acc[i][0] += av * b4[kk][0].x;
                acc[i][1] += av * b4[kk][0].y;
                acc[i][2] += av * b4[kk][0].z;
                acc[i][3] += av * b4[kk][0].w;
                acc[i][4] += av * b4[kk][1].x;
                acc[i][5] += av * b4[kk][1].y;
                acc[i][6] += av * b4[kk][1].z;
                acc[i][7] += av * b4[kk][1].w;
            }
        }
    }

    float bb[8];
    #pragma unroll
    for (int j = 0; j < 8; ++j) bb[j] = bias[c0 + j];

    #pragma unroll
    for (int i = 0; i < 8; ++i) {
        int row = rbase + r0 + i;
        if (row < n) {
            float4 o0, o1;
            o0.x = fmaxf(acc[i][0] + bb[0], 0.f);
            o0.y = fmaxf(acc[i][1] + bb[1], 0.f);
            o0.z = fmaxf(acc[i][2] + bb[2], 0.f);
            o0.w = fmaxf(acc[i][3] + bb[3], 0.f);
            o1.x = fmaxf(acc[i][4] + bb[4], 0.f);
            o1.y = fmaxf(acc[i][5] + bb[5], 0.f);
            o1.z = fmaxf(acc[i][6] + bb[6], 0.f);
            o1.w = fmaxf(acc[i][7] + bb[7], 0.f);
            reinterpret_cast<float4*>(out)[(size_t)row * 32 + (c0 >> 2)] = o0;
            reinterpret_cast<float4*>(out)[(size_t)row * 32 + (c0 >> 2) + 1] = o1;
        }
    }
}

static inline size_t align256(size_t v) { return (v + 255) & ~(size_t)255; }

extern "C" void kernel_launch(void* const* d_in, const int* in_sizes, int n_in,
                              void* d_out, int out_size, void* d_ws, size_t ws_size,
                              hipStream_t stream) {
    const float* x = (const float*)d_in[0];
    const int* ei = (const int*)d_in[1];        // harness: integer -> int32
    const float* w = (const float*)d_in[2];
    const float* W = (const float*)d_in[3];
    const float* b = (const float*)d_in[4];
    float* out = (float*)d_out;

    const int N = in_sizes[0] / 128;
    const int E = in_sizes[2];
    const int* row = ei;       // source
    const int* col = ei + E;   // target

    const int nScan = (N + 1023) / 1024;   // 98 for N=100000

    // Workspace partition, 256B-aligned regions; xbf2 last (optional).
    char* base = (char*)d_ws;
    size_t off = 0;
    unsigned long long* packed = (unsigned long long*)(base + off);
    off = align256(off + (size_t)N * 8);
    float* dinv = (float*)(base + off);         off = align256(off + (size_t)N * 4);
    int* cursor = (int*)(base + off);           off = align256(off + (size_t)N * 4);
    int* offs = (int*)(base + off);             off = align256(off + ((size_t)N + 1) * 4);
    int* blockSums = (int*)(base + off);        off = align256(off + 1024 * 4);
    int2* csr = (int2*)(base + off);            off = align256(off + (size_t)E * 8);
    unsigned int* xbf2 = (unsigned int*)(base + off);
    size_t need_bf16 = off + (size_t)N * 64 * 4;
    const bool use_bf16 = (ws_size >= need_bf16);

    const int B = 256;
    const int nx8 = (N * 128) / 8;   // 8 fp32 -> 4 packed bf16x2 per thread

    init_kernel<<<(N + B - 1) / B, B, 0, stream>>>(packed, cursor, N);
    if (use_bf16) {
        int nt = (E > nx8) ? E : nx8;
        hist_cvt_kernel<<<(nt + B - 1) / B, B, 0, stream>>>(col, w, packed, x, xbf2, E, nx8);
    } else {
        edge_hist<<<(E + B - 1) / B, B, 0, stream>>>(col, w, packed, E);
    }
    scan1_kernel<<<nScan, 256, 0, stream>>>(packed, dinv, offs, blockSums, N);
    scan2_kernel<<<1, 1024, 0, stream>>>(blockSums, nScan);
    scan3_kernel<<<nScan, 256, 0, stream>>>(offs, blockSums, N, E);
    scatter_kernel<<<(E + B - 1) / B, B, 0, stream>>>(row, col, w, dinv, offs, cursor,
                                                      csr, E);
    if (use_bf16) {
        agg_kernel_bf16<<<(N + 3) / 4, 256, 0, stream>>>(xbf2, dinv, offs, csr, out, N);
    } else {
        agg_kernel_f32<<<(N + 3) / 4, 256, 0, stream>>>(x, dinv, offs, csr, out, N);
    }
    gemm_inplace<<<(N + 127) / 128, 256, 0, stream>>>(out, W, b, out, N);
}

// Round 7
// 311.874 us; speedup vs baseline: 1.9666x; 1.2692x over previous
//
#include <hip/hip_runtime.h>

// ---------------------------------------------------------------------------
// GCNConv + ReLU, aggregate-then-transform (GCN is linear before the GEMM):
//   deg[c]  = 1 + sum_{e: col[e]=c} w[e]
//   dinv    = rsqrt(deg)
//   agg[c]  = dinv[c]^2 * x[c] + sum_{e: col[e]=c} (dinv[row]*w*dinv[c]) * x[row]
//   out     = relu(agg @ W + b)
// R4: packed 64-bit hist atomic (count hi32 | 8.24 fixed-point deg lo32).
// R5: bf16 gathers (x converted once, fused into hist's idle read pipe).
// R6: agg was LATENCY-bound (R5 halved FETCH, time -13% only; 1 outstanding
//     gather/wave). 8-way unrolled edge loop -> 8 gathers in flight per wave.
// ---------------------------------------------------------------------------

static __device__ __forceinline__ float fix2float(unsigned int v) {
    return (float)v * 5.9604644775390625e-8f;   // * 2^-24
}

// fp32 bits -> bf16 (RNE), packed pair (lo element in low 16 bits)
static __device__ __forceinline__ unsigned int pack_bf2(unsigned int lo, unsigned int hi) {
    unsigned int l = (lo + 0x7FFFu + ((lo >> 16) & 1u)) >> 16;
    unsigned int h = (hi + 0x7FFFu + ((hi >> 16) & 1u)) >> 16;
    return l | (h << 16);
}

static __device__ __forceinline__ float2 bf2_to_f2(unsigned int u) {
    union { unsigned int i; float f; } a, b;
    a.i = u << 16;
    b.i = u & 0xFFFF0000u;
    return make_float2(a.f, b.f);
}

__global__ void init_kernel(unsigned long long* __restrict__ packed,
                            int* __restrict__ cursor, int n) {
    int i = blockIdx.x * blockDim.x + threadIdx.x;
    if (i < n) {
        packed[i] = (unsigned long long)(1u << 24);  // deg = 1.0 (self-loop), count = 0
        cursor[i] = 0;
    }
}

// Fused: per-edge degree histogram (atomic pipe) + x -> bf16 conversion
// (read/write pipe). Thread t handles edge t and x dwords [8t, 8t+8).
__global__ void hist_cvt_kernel(const int* __restrict__ col,
                                const float* __restrict__ w,
                                unsigned long long* __restrict__ packed,
                                const float* __restrict__ x,
                                unsigned int* __restrict__ xbf2,  // N*64 packed pairs
                                int E, int nx8) {
    int t = blockIdx.x * blockDim.x + threadIdx.x;
    if (t < nx8) {
        const uint4* xin = reinterpret_cast<const uint4*>(x);
        uint4 a = xin[t * 2];
        uint4 b = xin[t * 2 + 1];
        uint4 o;
        o.x = pack_bf2(a.x, a.y);
        o.y = pack_bf2(a.z, a.w);
        o.z = pack_bf2(b.x, b.y);
        o.w = pack_bf2(b.z, b.w);
        reinterpret_cast<uint4*>(xbf2)[t] = o;
    }
    if (t < E) {
        unsigned int fx = (unsigned int)(w[t] * 16777216.0f);  // w in [0,1): < 2^24
        atomicAdd(&packed[col[t]], (1ULL << 32) | (unsigned long long)fx);
    }
}

// Plain hist (fallback when ws can't hold xbf2).
__global__ void edge_hist(const int* __restrict__ col,
                          const float* __restrict__ w,
                          unsigned long long* __restrict__ packed, int E) {
    int e = blockIdx.x * blockDim.x + threadIdx.x;
    if (e < E) {
        unsigned int fx = (unsigned int)(w[e] * 16777216.0f);
        atomicAdd(&packed[col[e]], (1ULL << 32) | (unsigned long long)fx);
    }
}

// Block-local exclusive scan of 1024-element chunks: counts = packed.hi -> offs
// (partial) + blockSums; fused dinv[i] = rsqrt(packed.lo * 2^-24).
__launch_bounds__(256)
__global__ void scan1_kernel(const unsigned long long* __restrict__ packed,
                             float* __restrict__ dinv,
                             int* __restrict__ offs, int* __restrict__ blockSums, int n) {
    __shared__ int waveSums[4];
    const int tid = threadIdx.x;
    const int lane = tid & 63;
    const int wv = tid >> 6;
    const int base = blockIdx.x * 1024 + tid * 4;

    int c0 = 0, c1 = 0, c2 = 0, c3 = 0;
    if (base + 3 < n) {
        unsigned long long p0 = packed[base];
        unsigned long long p1 = packed[base + 1];
        unsigned long long p2 = packed[base + 2];
        unsigned long long p3 = packed[base + 3];
        c0 = (int)(p0 >> 32); c1 = (int)(p1 >> 32);
        c2 = (int)(p2 >> 32); c3 = (int)(p3 >> 32);
        float4 d;
        d.x = rsqrtf(fix2float((unsigned int)p0));
        d.y = rsqrtf(fix2float((unsigned int)p1));
        d.z = rsqrtf(fix2float((unsigned int)p2));
        d.w = rsqrtf(fix2float((unsigned int)p3));
        *reinterpret_cast<float4*>(&dinv[base]) = d;
    } else {
        for (int t = 0; t < 4; ++t) {
            if (base + t < n) {
                unsigned long long p = packed[base + t];
                int cv = (int)(p >> 32);
                if (t == 0) c0 = cv; else if (t == 1) c1 = cv;
                else if (t == 2) c2 = cv;  else c3 = cv;
                dinv[base + t] = rsqrtf(fix2float((unsigned int)p));
            }
        }
    }
    int s1 = c0 + c1, s2 = s1 + c2, s3 = s2 + c3;

    int incl = s3;
    #pragma unroll
    for (int off = 1; off < 64; off <<= 1) {
        int v = __shfl_up(incl, off);
        if (lane >= off) incl += v;
    }
    if (lane == 63) waveSums[wv] = incl;
    __syncthreads();
    if (tid == 0) {
        int a = 0;
        #pragma unroll
        for (int i = 0; i < 4; ++i) { int t = waveSums[i]; waveSums[i] = a; a += t; }
        blockSums[blockIdx.x] = a;
    }
    __syncthreads();

    int ex = waveSums[wv] + (incl - s3);
    if (base + 3 < n) {
        int4 o;
        o.x = ex; o.y = ex + c0; o.z = ex + s1; o.w = ex + s2;
        *reinterpret_cast<int4*>(&offs[base]) = o;
    } else {
        if (base     < n) offs[base]     = ex;
        if (base + 1 < n) offs[base + 1] = ex + c0;
        if (base + 2 < n) offs[base + 2] = ex + s1;
    }
}

__global__ void scan2_kernel(int* __restrict__ blockSums, int nb) {
    __shared__ int lds[1024];
    int tid = threadIdx.x;
    if (tid < nb) lds[tid] = blockSums[tid];
    __syncthreads();
    if (tid == 0) {
        int a = 0;
        for (int i = 0; i < nb; ++i) { int t = lds[i]; lds[i] = a; a += t; }
    }
    __syncthreads();
    if (tid < nb) blockSums[tid] = lds[tid];
}

__launch_bounds__(256)
__global__ void scan3_kernel(int* __restrict__ offs, const int* __restrict__ blockSums,
                             int n, int total) {
    int i = (blockIdx.x * 256 + threadIdx.x) * 4;
    int bs = blockSums[blockIdx.x];
    if (i + 3 < n) {
        int4 v = *reinterpret_cast<const int4*>(&offs[i]);
        v.x += bs; v.y += bs; v.z += bs; v.w += bs;
        *reinterpret_cast<int4*>(&offs[i]) = v;
    } else {
        if (i     < n) offs[i]     += bs;
        if (i + 1 < n) offs[i + 1] += bs;
        if (i + 2 < n) offs[i + 2] += bs;
    }
    if (blockIdx.x == 0 && threadIdx.x == 0) offs[n] = total;
}

__global__ void scatter_kernel(const int* __restrict__ row,
                               const int* __restrict__ col,
                               const float* __restrict__ w,
                               const float* __restrict__ dinv,
                               const int* __restrict__ offs,
                               int* __restrict__ cursor,
                               int2* __restrict__ csr, int E) {
    int e = blockIdx.x * blockDim.x + threadIdx.x;
    if (e < E) {
        int r = row[e];
        int c = col[e];
        float nw = dinv[r] * w[e] * dinv[c];
        int p = offs[c] + atomicAdd(&cursor[c], 1);
        csr[p] = make_int2(r, __float_as_int(nw));   // one 8B store
    }
}

// One wave per node, bf16 gathers, 8-way ILP: lane owns channels {2l, 2l+1}.
__launch_bounds__(256)
__global__ void agg_kernel_bf16(const unsigned int* __restrict__ xbf2,
                                const float* __restrict__ dinv,
                                const int* __restrict__ offs, const int2* __restrict__ csr,
                                float* __restrict__ aggOut, int n) {
    int wid = (blockIdx.x * blockDim.x + threadIdx.x) >> 6;
    int lane = threadIdx.x & 63;
    if (wid >= n) return;

    float di = dinv[wid];
    float2 xi = bf2_to_f2(xbf2[(size_t)wid * 64 + lane]);
    float sw = di * di;   // self-loop: dinv^2 * 1.0
    float ax0 = sw * xi.x, ay0 = sw * xi.y;   // two independent acc pairs
    float ax1 = 0.f,       ay1 = 0.f;

    int s = offs[wid];
    int e = offs[wid + 1];
    int j = s;

    // 8-way: 8 independent gathers in flight per wave
    for (; j + 8 <= e; j += 8) {
        int2 m0 = csr[j + 0]; int2 m1 = csr[j + 1];
        int2 m2 = csr[j + 2]; int2 m3 = csr[j + 3];
        int2 m4 = csr[j + 4]; int2 m5 = csr[j + 5];
        int2 m6 = csr[j + 6]; int2 m7 = csr[j + 7];
        unsigned int v0 = xbf2[(size_t)m0.x * 64 + lane];
        unsigned int v1 = xbf2[(size_t)m1.x * 64 + lane];
        unsigned int v2 = xbf2[(size_t)m2.x * 64 + lane];
        unsigned int v3 = xbf2[(size_t)m3.x * 64 + lane];
        unsigned int v4 = xbf2[(size_t)m4.x * 64 + lane];
        unsigned int v5 = xbf2[(size_t)m5.x * 64 + lane];
        unsigned int v6 = xbf2[(size_t)m6.x * 64 + lane];
        unsigned int v7 = xbf2[(size_t)m7.x * 64 + lane];
        float2 f0 = bf2_to_f2(v0); float2 f1 = bf2_to_f2(v1);
        float2 f2 = bf2_to_f2(v2); float2 f3 = bf2_to_f2(v3);
        float2 f4 = bf2_to_f2(v4); float2 f5 = bf2_to_f2(v5);
        float2 f6 = bf2_to_f2(v6); float2 f7 = bf2_to_f2(v7);
        float w0 = __int_as_float(m0.y); float w1 = __int_as_float(m1.y);
        float w2 = __int_as_float(m2.y); float w3 = __int_as_float(m3.y);
        float w4 = __int_as_float(m4.y); float w5 = __int_as_float(m5.y);
        float w6 = __int_as_float(m6.y); float w7 = __int_as_float(m7.y);
        ax0 += w0 * f0.x; ay0 += w0 * f0.y;
        ax1 += w1 * f1.x; ay1 += w1 * f1.y;
        ax0 += w2 * f2.x; ay0 += w2 * f2.y;
        ax1 += w3 * f3.x; ay1 += w3 * f3.y;
        ax0 += w4 * f4.x; ay0 += w4 * f4.y;
        ax1 += w5 * f5.x; ay1 += w5 * f5.y;
        ax0 += w6 * f6.x; ay0 += w6 * f6.y;
        ax1 += w7 * f7.x; ay1 += w7 * f7.y;
    }
    // 2-way
    for (; j + 2 <= e; j += 2) {
        int2 m0 = csr[j + 0]; int2 m1 = csr[j + 1];
        unsigned int v0 = xbf2[(size_t)m0.x * 64 + lane];
        unsigned int v1 = xbf2[(size_t)m1.x * 64 + lane];
        float2 f0 = bf2_to_f2(v0); float2 f1 = bf2_to_f2(v1);
        float w0 = __int_as_float(m0.y); float w1 = __int_as_float(m1.y);
        ax0 += w0 * f0.x; ay0 += w0 * f0.y;
        ax1 += w1 * f1.x; ay1 += w1 * f1.y;
    }
    // scalar tail
    for (; j < e; ++j) {
        int2 m = csr[j];
        float2 f = bf2_to_f2(xbf2[(size_t)m.x * 64 + lane]);
        float wn = __int_as_float(m.y);
        ax0 += wn * f.x; ay0 += wn * f.y;
    }

    float2 acc;
    acc.x = ax0 + ax1;
    acc.y = ay0 + ay1;
    *reinterpret_cast<float2*>(&aggOut[(size_t)wid * 128 + lane * 2]) = acc;
}

// fp32 fallback (ws too small for xbf2), same ILP structure
__launch_bounds__(256)
__global__ void agg_kernel_f32(const float* __restrict__ x, const float* __restrict__ dinv,
                               const int* __restrict__ offs, const int2* __restrict__ csr,
                               float* __restrict__ aggOut, int n) {
    int wid = (blockIdx.x * blockDim.x + threadIdx.x) >> 6;
    int lane = threadIdx.x & 63;
    if (wid >= n) return;

    float di = dinv[wid];
    float2 xi = *reinterpret_cast<const float2*>(&x[(size_t)wid * 128 + lane * 2]);
    float sw = di * di;
    float ax0 = sw * xi.x, ay0 = sw * xi.y;
    float ax1 = 0.f,       ay1 = 0.f;

    int s = offs[wid];
    int e = offs[wid + 1];
    int j = s;
    for (; j + 4 <= e; j += 4) {
        int2 m0 = csr[j + 0]; int2 m1 = csr[j + 1];
        int2 m2 = csr[j + 2]; int2 m3 = csr[j + 3];
        float2 f0 = *reinterpret_cast<const float2*>(&x[(size_t)m0.x * 128 + lane * 2]);
        float2 f1 = *reinterpret_cast<const float2*>(&x[(size_t)m1.x * 128 + lane * 2]);
        float2 f2 = *reinterpret_cast<const float2*>(&x[(size_t)m2.x * 128 + lane * 2]);
        float2 f3 = *reinterpret_cast<const float2*>(&x[(size_t)m3.x * 128 + lane * 2]);
        float w0 = __int_as_float(m0.y); float w1 = __int_as_float(m1.y);
        float w2 = __int_as_float(m2.y); float w3 = __int_as_float(m3.y);
        ax0 += w0 * f0.x; ay0 += w0 * f0.y;
        ax1 += w1 * f1.x; ay1 += w1 * f1.y;
        ax0 += w2 * f2.x; ay0 += w2 * f2.y;
        ax1 += w3 * f3.x; ay1 += w3 * f3.y;
    }
    for (; j < e; ++j) {
        int2 m = csr[j];
        float wn = __int_as_float(m.y);
        float2 f = *reinterpret_cast<const float2*>(&x[(size_t)m.x * 128 + lane * 2]);
        ax0 += wn * f.x; ay0 += wn * f.y;
    }
    float2 acc;
    acc.x = ax0 + ax1;
    acc.y = ay0 + ay1;
    *reinterpret_cast<float2*>(&aggOut[(size_t)wid * 128 + lane * 2]) = acc;
}

// out = relu(in @ W + b), in-place safe: block stages its 128-row tile in LDS.
__launch_bounds__(256)
__global__ void gemm_inplace(const float* __restrict__ in, const float* __restrict__ W,
                             const float* __restrict__ bias,
                             float* __restrict__ out, int n) {
    __shared__ float xs[128 * 128];  // 64 KiB
    __shared__ float wl[128 * 128];  // 64 KiB
    const int tid = threadIdx.x;
    const int rbase = blockIdx.x * 128;

    #pragma unroll
    for (int i = 0; i < 16; ++i) {
        int f = tid + i * 256;
        int row = f >> 5;
        int c4 = f & 31;
        float4 v = make_float4(0.f, 0.f, 0.f, 0.f);
        if (rbase + row < n)
            v = reinterpret_cast<const float4*>(in)[(size_t)(rbase + row) * 32 + c4];
        reinterpret_cast<float4*>(xs)[row * 32 + c4] = v;
        reinterpret_cast<float4*>(wl)[f] = reinterpret_cast<const float4*>(W)[f];
    }
    __syncthreads();

    const int tx = tid & 15;
    const int ty = tid >> 4;
    const int c0 = tx * 8;
    const int r0 = ty * 8;

    float acc[8][8];
    #pragma unroll
    for (int i = 0; i < 8; ++i)
        #pragma unroll
        for (int j = 0; j < 8; ++j) acc[i][j] = 0.f;

    for (int k = 0; k < 128; k += 4) {
        float4 a[8];
        float4 b4[4][2];
        #pragma unroll
        for (int i = 0; i < 8; ++i)
            a[i] = *reinterpret_cast<const float4*>(&xs[(r0 + i) * 128 + k]);
        #pragma unroll
        for (int kk = 0; kk < 4; ++kk) {
            b4[kk][0] = *reinterpret_cast<const float4*>(&wl[(k + kk) * 128 + c0]);
            b4[kk][1] = *reinterpret_cast<const float4*>(&wl[(k + kk) * 128 + c0 + 4]);
        }
        #pragma unroll
        for (int kk = 0; kk < 4; ++kk) {
            #pragma unroll
            for (int i = 0; i < 8; ++i) {
                float av = reinterpret_cast<const float*>(&a[i])[kk];
                acc[i][0] += av * b4[kk][0].x;
                acc[i][1] += av * b4[kk][0].y;
                acc[i][2] += av * b4[kk][0].z;
                acc[i][3] += av * b4[kk][0].w;
                acc[i][4] += av * b4[kk][1].x;
                acc[i][5] += av * b4[kk][1].y;
                acc[i][6] += av * b4[kk][1].z;
                acc[i][7] += av * b4[kk][1].w;
            }
        }
    }

    float bb[8];
    #pragma unroll
    for (int j = 0; j < 8; ++j) bb[j] = bias[c0 + j];

    #pragma unroll
    for (int i = 0; i < 8; ++i) {
        int row = rbase + r0 + i;
        if (row < n) {
            float4 o0, o1;
            o0.x = fmaxf(acc[i][0] + bb[0], 0.f);
            o0.y = fmaxf(acc[i][1] + bb[1], 0.f);
            o0.z = fmaxf(acc[i][2] + bb[2], 0.f);
            o0.w = fmaxf(acc[i][3] + bb[3], 0.f);
            o1.x = fmaxf(acc[i][4] + bb[4], 0.f);
            o1.y = fmaxf(acc[i][5] + bb[5], 0.f);
            o1.z = fmaxf(acc[i][6] + bb[6], 0.f);
            o1.w = fmaxf(acc[i][7] + bb[7], 0.f);
            reinterpret_cast<float4*>(out)[(size_t)row * 32 + (c0 >> 2)] = o0;
            reinterpret_cast<float4*>(out)[(size_t)row * 32 + (c0 >> 2) + 1] = o1;
        }
    }
}

static inline size_t align256(size_t v) { return (v + 255) & ~(size_t)255; }

extern "C" void kernel_launch(void* const* d_in, const int* in_sizes, int n_in,
                              void* d_out, int out_size, void* d_ws, size_t ws_size,
                              hipStream_t stream) {
    const float* x = (const float*)d_in[0];
    const int* ei = (const int*)d_in[1];        // harness: integer -> int32
    const float* w = (const float*)d_in[2];
    const float* W = (const float*)d_in[3];
    const float* b = (const float*)d_in[4];
    float* out = (float*)d_out;

    const int N = in_sizes[0] / 128;
    const int E = in_sizes[2];
    const int* row = ei;       // source
    const int* col = ei + E;   // target

    const int nScan = (N + 1023) / 1024;   // 98 for N=100000

    // Workspace partition, 256B-aligned regions; xbf2 last (optional).
    char* base = (char*)d_ws;
    size_t off = 0;
    unsigned long long* packed = (unsigned long long*)(base + off);
    off = align256(off + (size_t)N * 8);
    float* dinv = (float*)(base + off);         off = align256(off + (size_t)N * 4);
    int* cursor = (int*)(base + off);           off = align256(off + (size_t)N * 4);
    int* offs = (int*)(base + off);             off = align256(off + ((size_t)N + 1) * 4);
    int* blockSums = (int*)(base + off);        off = align256(off + 1024 * 4);
    int2* csr = (int2*)(base + off);            off = align256(off + (size_t)E * 8);
    unsigned int* xbf2 = (unsigned int*)(base + off);
    size_t need_bf16 = off + (size_t)N * 64 * 4;
    const bool use_bf16 = (ws_size >= need_bf16);

    const int B = 256;
    const int nx8 = (N * 128) / 8;   // 8 fp32 -> 4 packed bf16x2 per thread

    init_kernel<<<(N + B - 1) / B, B, 0, stream>>>(packed, cursor, N);
    if (use_bf16) {
        int nt = (E > nx8) ? E : nx8;
        hist_cvt_kernel<<<(nt + B - 1) / B, B, 0, stream>>>(col, w, packed, x, xbf2, E, nx8);
    } else {
        edge_hist<<<(E + B - 1) / B, B, 0, stream>>>(col, w, packed, E);
    }
    scan1_kernel<<<nScan, 256, 0, stream>>>(packed, dinv, offs, blockSums, N);
    scan2_kernel<<<1, 1024, 0, stream>>>(blockSums, nScan);
    scan3_kernel<<<nScan, 256, 0, stream>>>(offs, blockSums, N, E);
    scatter_kernel<<<(E + B - 1) / B, B, 0, stream>>>(row, col, w, dinv, offs, cursor,
                                                      csr, E);
    if (use_bf16) {
        agg_kernel_bf16<<<(N + 3) / 4, 256, 0, stream>>>(xbf2, dinv, offs, csr, out, N);
    } else {
        agg_kernel_f32<<<(N + 3) / 4, 256, 0, stream>>>(x, dinv, offs, csr, out, N);
    }
    gemm_inplace<<<(N + 127) / 128, 256, 0, stream>>>(out, W, b, out, N);
}

// Round 8
// 302.410 us; speedup vs baseline: 2.0281x; 1.0313x over previous
//
#include <hip/hip_runtime.h>

// ---------------------------------------------------------------------------
// GCNConv + ReLU, aggregate-then-transform (GCN is linear before the GEMM):
//   deg[c]  = 1 + sum_{e: col[e]=c} w[e]
//   dinv    = rsqrt(deg)
//   agg[c]  = dinv[c]^2 * x[c] + sum_{e: col[e]=c} (dinv[row]*w*dinv[c]) * x[row]
//   out     = relu(agg @ W + b)
// R4: packed 64-bit hist atomic. R5: bf16 gathers. R6: 8-way ILP in agg.
// R7: fp32 VALU GEMM (99us, 1 blk/CU from 128KB LDS, 6.4M bank conflicts) ->
//     MFMA bf16x3 GEMM: A split hi/lo IN REGISTERS from fp32 d_out (in-place,
//     wave owns its rows), W split hi/lo in LDS (64KB, transposed+swizzled).
//     out = ah@Wh + ah@Wl + al@Wh  => ~fp32 accuracy, absmax unchanged.
// ---------------------------------------------------------------------------

typedef __attribute__((ext_vector_type(8))) short short8v;   // 8 bf16 (4 VGPR)
typedef __attribute__((ext_vector_type(4))) float f32x4;

static __device__ __forceinline__ float fix2float(unsigned int v) {
    return (float)v * 5.9604644775390625e-8f;   // * 2^-24
}

static __device__ __forceinline__ unsigned short bf16_rne(float f) {
    unsigned int u = __float_as_uint(f);
    u += 0x7FFFu + ((u >> 16) & 1u);
    return (unsigned short)(u >> 16);
}

static __device__ __forceinline__ float bf16f(unsigned short h) {
    return __uint_as_float((unsigned int)h << 16);
}

// fp32 bits -> bf16 (RNE), packed pair (lo element in low 16 bits)
static __device__ __forceinline__ unsigned int pack_bf2(unsigned int lo, unsigned int hi) {
    unsigned int l = (lo + 0x7FFFu + ((lo >> 16) & 1u)) >> 16;
    unsigned int h = (hi + 0x7FFFu + ((hi >> 16) & 1u)) >> 16;
    return l | (h << 16);
}

static __device__ __forceinline__ float2 bf2_to_f2(unsigned int u) {
    union { unsigned int i; float f; } a, b;
    a.i = u << 16;
    b.i = u & 0xFFFF0000u;
    return make_float2(a.f, b.f);
}

__global__ void init_kernel(unsigned long long* __restrict__ packed,
                            int* __restrict__ cursor, int n) {
    int i = blockIdx.x * blockDim.x + threadIdx.x;
    if (i < n) {
        packed[i] = (unsigned long long)(1u << 24);  // deg = 1.0 (self-loop), count = 0
        cursor[i] = 0;
    }
}

// Fused: per-edge degree histogram (atomic pipe) + x -> bf16 conversion
// (read/write pipe). Thread t handles edge t and x dwords [8t, 8t+8).
__global__ void hist_cvt_kernel(const int* __restrict__ col,
                                const float* __restrict__ w,
                                unsigned long long* __restrict__ packed,
                                const float* __restrict__ x,
                                unsigned int* __restrict__ xbf2,  // N*64 packed pairs
                                int E, int nx8) {
    int t = blockIdx.x * blockDim.x + threadIdx.x;
    if (t < nx8) {
        const uint4* xin = reinterpret_cast<const uint4*>(x);
        uint4 a = xin[t * 2];
        uint4 b = xin[t * 2 + 1];
        uint4 o;
        o.x = pack_bf2(a.x, a.y);
        o.y = pack_bf2(a.z, a.w);
        o.z = pack_bf2(b.x, b.y);
        o.w = pack_bf2(b.z, b.w);
        reinterpret_cast<uint4*>(xbf2)[t] = o;
    }
    if (t < E) {
        unsigned int fx = (unsigned int)(w[t] * 16777216.0f);  // w in [0,1): < 2^24
        atomicAdd(&packed[col[t]], (1ULL << 32) | (unsigned long long)fx);
    }
}

// Plain hist (fallback when ws can't hold xbf2).
__global__ void edge_hist(const int* __restrict__ col,
                          const float* __restrict__ w,
                          unsigned long long* __restrict__ packed, int E) {
    int e = blockIdx.x * blockDim.x + threadIdx.x;
    if (e < E) {
        unsigned int fx = (unsigned int)(w[e] * 16777216.0f);
        atomicAdd(&packed[col[e]], (1ULL << 32) | (unsigned long long)fx);
    }
}

// Block-local exclusive scan of 1024-element chunks: counts = packed.hi -> offs
// (partial) + blockSums; fused dinv[i] = rsqrt(packed.lo * 2^-24).
__launch_bounds__(256)
__global__ void scan1_kernel(const unsigned long long* __restrict__ packed,
                             float* __restrict__ dinv,
                             int* __restrict__ offs, int* __restrict__ blockSums, int n) {
    __shared__ int waveSums[4];
    const int tid = threadIdx.x;
    const int lane = tid & 63;
    const int wv = tid >> 6;
    const int base = blockIdx.x * 1024 + tid * 4;

    int c0 = 0, c1 = 0, c2 = 0, c3 = 0;
    if (base + 3 < n) {
        unsigned long long p0 = packed[base];
        unsigned long long p1 = packed[base + 1];
        unsigned long long p2 = packed[base + 2];
        unsigned long long p3 = packed[base + 3];
        c0 = (int)(p0 >> 32); c1 = (int)(p1 >> 32);
        c2 = (int)(p2 >> 32); c3 = (int)(p3 >> 32);
        float4 d;
        d.x = rsqrtf(fix2float((unsigned int)p0));
        d.y = rsqrtf(fix2float((unsigned int)p1));
        d.z = rsqrtf(fix2float((unsigned int)p2));
        d.w = rsqrtf(fix2float((unsigned int)p3));
        *reinterpret_cast<float4*>(&dinv[base]) = d;
    } else {
        for (int t = 0; t < 4; ++t) {
            if (base + t < n) {
                unsigned long long p = packed[base + t];
                int cv = (int)(p >> 32);
                if (t == 0) c0 = cv; else if (t == 1) c1 = cv;
                else if (t == 2) c2 = cv;  else c3 = cv;
                dinv[base + t] = rsqrtf(fix2float((unsigned int)p));
            }
        }
    }
    int s1 = c0 + c1, s2 = s1 + c2, s3 = s2 + c3;

    int incl = s3;
    #pragma unroll
    for (int off = 1; off < 64; off <<= 1) {
        int v = __shfl_up(incl, off);
        if (lane >= off) incl += v;
    }
    if (lane == 63) waveSums[wv] = incl;
    __syncthreads();
    if (tid == 0) {
        int a = 0;
        #pragma unroll
        for (int i = 0; i < 4; ++i) { int t = waveSums[i]; waveSums[i] = a; a += t; }
        blockSums[blockIdx.x] = a;
    }
    __syncthreads();

    int ex = waveSums[wv] + (incl - s3);
    if (base + 3 < n) {
        int4 o;
        o.x = ex; o.y = ex + c0; o.z = ex + s1; o.w = ex + s2;
        *reinterpret_cast<int4*>(&offs[base]) = o;
    } else {
        if (base     < n) offs[base]     = ex;
        if (base + 1 < n) offs[base + 1] = ex + c0;
        if (base + 2 < n) offs[base + 2] = ex + s1;
    }
}

__global__ void scan2_kernel(int* __restrict__ blockSums, int nb) {
    __shared__ int lds[1024];
    int tid = threadIdx.x;
    if (tid < nb) lds[tid] = blockSums[tid];
    __syncthreads();
    if (tid == 0) {
        int a = 0;
        for (int i = 0; i < nb; ++i) { int t = lds[i]; lds[i] = a; a += t; }
    }
    __syncthreads();
    if (tid < nb) blockSums[tid] = lds[tid];
}

__launch_bounds__(256)
__global__ void scan3_kernel(int* __restrict__ offs, const int* __restrict__ blockSums,
                             int n, int total) {
    int i = (blockIdx.x * 256 + threadIdx.x) * 4;
    int bs = blockSums[blockIdx.x];
    if (i + 3 < n) {
        int4 v = *reinterpret_cast<const int4*>(&offs[i]);
        v.x += bs; v.y += bs; v.z += bs; v.w += bs;
        *reinterpret_cast<int4*>(&offs[i]) = v;
    } else {
        if (i     < n) offs[i]     += bs;
        if (i + 1 < n) offs[i + 1] += bs;
        if (i + 2 < n) offs[i + 2] += bs;
    }
    if (blockIdx.x == 0 && threadIdx.x == 0) offs[n] = total;
}

__global__ void scatter_kernel(const int* __restrict__ row,
                               const int* __restrict__ col,
                               const float* __restrict__ w,
                               const float* __restrict__ dinv,
                               const int* __restrict__ offs,
                               int* __restrict__ cursor,
                               int2* __restrict__ csr, int E) {
    int e = blockIdx.x * blockDim.x + threadIdx.x;
    if (e < E) {
        int r = row[e];
        int c = col[e];
        float nw = dinv[r] * w[e] * dinv[c];
        int p = offs[c] + atomicAdd(&cursor[c], 1);
        csr[p] = make_int2(r, __float_as_int(nw));   // one 8B store
    }
}

// One wave per node, bf16 gathers, 8-way ILP: lane owns channels {2l, 2l+1}.
__launch_bounds__(256)
__global__ void agg_kernel_bf16(const unsigned int* __restrict__ xbf2,
                                const float* __restrict__ dinv,
                                const int* __restrict__ offs, const int2* __restrict__ csr,
                                float* __restrict__ aggOut, int n) {
    int wid = (blockIdx.x * blockDim.x + threadIdx.x) >> 6;
    int lane = threadIdx.x & 63;
    if (wid >= n) return;

    float di = dinv[wid];
    float2 xi = bf2_to_f2(xbf2[(size_t)wid * 64 + lane]);
    float sw = di * di;   // self-loop: dinv^2 * 1.0
    float ax0 = sw * xi.x, ay0 = sw * xi.y;   // two independent acc pairs
    float ax1 = 0.f,       ay1 = 0.f;

    int s = offs[wid];
    int e = offs[wid + 1];
    int j = s;

    // 8-way: 8 independent gathers in flight per wave
    for (; j + 8 <= e; j += 8) {
        int2 m0 = csr[j + 0]; int2 m1 = csr[j + 1];
        int2 m2 = csr[j + 2]; int2 m3 = csr[j + 3];
        int2 m4 = csr[j + 4]; int2 m5 = csr[j + 5];
        int2 m6 = csr[j + 6]; int2 m7 = csr[j + 7];
        unsigned int v0 = xbf2[(size_t)m0.x * 64 + lane];
        unsigned int v1 = xbf2[(size_t)m1.x * 64 + lane];
        unsigned int v2 = xbf2[(size_t)m2.x * 64 + lane];
        unsigned int v3 = xbf2[(size_t)m3.x * 64 + lane];
        unsigned int v4 = xbf2[(size_t)m4.x * 64 + lane];
        unsigned int v5 = xbf2[(size_t)m5.x * 64 + lane];
        unsigned int v6 = xbf2[(size_t)m6.x * 64 + lane];
        unsigned int v7 = xbf2[(size_t)m7.x * 64 + lane];
        float2 f0 = bf2_to_f2(v0); float2 f1 = bf2_to_f2(v1);
        float2 f2 = bf2_to_f2(v2); float2 f3 = bf2_to_f2(v3);
        float2 f4 = bf2_to_f2(v4); float2 f5 = bf2_to_f2(v5);
        float2 f6 = bf2_to_f2(v6); float2 f7 = bf2_to_f2(v7);
        float w0 = __int_as_float(m0.y); float w1 = __int_as_float(m1.y);
        float w2 = __int_as_float(m2.y); float w3 = __int_as_float(m3.y);
        float w4 = __int_as_float(m4.y); float w5 = __int_as_float(m5.y);
        float w6 = __int_as_float(m6.y); float w7 = __int_as_float(m7.y);
        ax0 += w0 * f0.x; ay0 += w0 * f0.y;
        ax1 += w1 * f1.x; ay1 += w1 * f1.y;
        ax0 += w2 * f2.x; ay0 += w2 * f2.y;
        ax1 += w3 * f3.x; ay1 += w3 * f3.y;
        ax0 += w4 * f4.x; ay0 += w4 * f4.y;
        ax1 += w5 * f5.x; ay1 += w5 * f5.y;
        ax0 += w6 * f6.x; ay0 += w6 * f6.y;
        ax1 += w7 * f7.x; ay1 += w7 * f7.y;
    }
    // 2-way
    for (; j + 2 <= e; j += 2) {
        int2 m0 = csr[j + 0]; int2 m1 = csr[j + 1];
        unsigned int v0 = xbf2[(size_t)m0.x * 64 + lane];
        unsigned int v1 = xbf2[(size_t)m1.x * 64 + lane];
        float2 f0 = bf2_to_f2(v0); float2 f1 = bf2_to_f2(v1);
        float w0 = __int_as_float(m0.y); float w1 = __int_as_float(m1.y);
        ax0 += w0 * f0.x; ay0 += w0 * f0.y;
        ax1 += w1 * f1.x; ay1 += w1 * f1.y;
    }
    // scalar tail
    for (; j < e; ++j) {
        int2 m = csr[j];
        float2 f = bf2_to_f2(xbf2[(size_t)m.x * 64 + lane]);
        float wn = __int_as_float(m.y);
        ax0 += wn * f.x; ay0 += wn * f.y;
    }

    float2 acc;
    acc.x = ax0 + ax1;
    acc.y = ay0 + ay1;
    *reinterpret_cast<float2*>(&aggOut[(size_t)wid * 128 + lane * 2]) = acc;
}

// fp32 fallback (ws too small for xbf2), same ILP structure
__launch_bounds__(256)
__global__ void agg_kernel_f32(const float* __restrict__ x, const float* __restrict__ dinv,
                               const int* __restrict__ offs, const int2* __restrict__ csr,
                               float* __restrict__ aggOut, int n) {
    int wid = (blockIdx.x * blockDim.x + threadIdx.x) >> 6;
    int lane = threadIdx.x & 63;
    if (wid >= n) return;

    float di = dinv[wid];
    float2 xi = *reinterpret_cast<const float2*>(&x[(size_t)wid * 128 + lane * 2]);
    float sw = di * di;
    float ax0 = sw * xi.x, ay0 = sw * xi.y;
    float ax1 = 0.f,       ay1 = 0.f;

    int s = offs[wid];
    int e = offs[wid + 1];
    int j = s;
    for (; j + 4 <= e; j += 4) {
        int2 m0 = csr[j + 0]; int2 m1 = csr[j + 1];
        int2 m2 = csr[j + 2]; int2 m3 = csr[j + 3];
        float2 f0 = *reinterpret_cast<const float2*>(&x[(size_t)m0.x * 128 + lane * 2]);
        float2 f1 = *reinterpret_cast<const float2*>(&x[(size_t)m1.x * 128 + lane * 2]);
        float2 f2 = *reinterpret_cast<const float2*>(&x[(size_t)m2.x * 128 + lane * 2]);
        float2 f3 = *reinterpret_cast<const float2*>(&x[(size_t)m3.x * 128 + lane * 2]);
        float w0 = __int_as_float(m0.y); float w1 = __int_as_float(m1.y);
        float w2 = __int_as_float(m2.y); float w3 = __int_as_float(m3.y);
        ax0 += w0 * f0.x; ay0 += w0 * f0.y;
        ax1 += w1 * f1.x; ay1 += w1 * f1.y;
        ax0 += w2 * f2.x; ay0 += w2 * f2.y;
        ax1 += w3 * f3.x; ay1 += w3 * f3.y;
    }
    for (; j < e; ++j) {
        int2 m = csr[j];
        float wn = __int_as_float(m.y);
        float2 f = *reinterpret_cast<const float2*>(&x[(size_t)m.x * 128 + lane * 2]);
        ax0 += wn * f.x; ay0 += wn * f.y;
    }
    float2 acc;
    acc.x = ax0 + ax1;
    acc.y = ay0 + ay1;
    *reinterpret_cast<float2*>(&aggOut[(size_t)wid * 128 + lane * 2]) = acc;
}

// ---------------------------------------------------------------------------
// MFMA GEMM, in-place on io (= d_out holding fp32 agg):
//   io = relu(io @ W + b), via bf16x3: ah@Wh + ah@Wl + al@Wh.
// Block: 256 thr = 4 waves; each wave owns a 16-row slab (reads its own rows,
// writes its own rows -> in-place safe). W transposed hi/lo in LDS, XOR-swizzled.
// ---------------------------------------------------------------------------
__launch_bounds__(256)
__global__ void gemm_mfma(const float* __restrict__ Wm, const float* __restrict__ bias,
                          float* __restrict__ io, int n) {
    __shared__ unsigned short Wt[2][128 * 128];   // [hi/lo][c][k] bf16, swizzled

    const int tid = threadIdx.x;

    // Stage W: read row-major float4s (coalesced), split hi/lo, write transposed.
    #pragma unroll
    for (int i = 0; i < 16; ++i) {
        int f = tid + i * 256;           // float4 id, 0..4095
        int k = f >> 5;                  // 0..127
        int c4 = (f & 31) * 4;           // col base
        float4 v = reinterpret_cast<const float4*>(Wm)[f];
        float vv[4] = {v.x, v.y, v.z, v.w};
        #pragma unroll
        for (int j = 0; j < 4; ++j) {
            int c = c4 + j;
            unsigned short hi = bf16_rne(vv[j]);
            unsigned short lo = bf16_rne(vv[j] - bf16f(hi));
            int byte = (c * 256 + k * 2) ^ ((c & 7) << 4);
            Wt[0][byte >> 1] = hi;
            Wt[1][byte >> 1] = lo;
        }
    }
    __syncthreads();

    const int wv = tid >> 6;
    const int l = tid & 63;
    const int row0 = (blockIdx.x * 4 + wv) * 16;   // this wave's 16-row slab
    if (row0 >= n) return;

    const int arow = row0 + (l & 15);
    const int koff = (l >> 4) * 8;                 // k sub-offset within 32-chunk
    const bool rok = arow < n;

    // Load A slab fp32, split into hi/lo bf16 fragments (registers only).
    short8v ahi[4], alo[4];
    #pragma unroll
    for (int kc = 0; kc < 4; ++kc) {
        float4 p0 = make_float4(0.f, 0.f, 0.f, 0.f);
        float4 p1 = p0;
        if (rok) {
            const float* src = io + (size_t)arow * 128 + kc * 32 + koff;
            p0 = *reinterpret_cast<const float4*>(src);
            p1 = *reinterpret_cast<const float4*>(src + 4);
        }
        float a8[8] = {p0.x, p0.y, p0.z, p0.w, p1.x, p1.y, p1.z, p1.w};
        #pragma unroll
        for (int j = 0; j < 8; ++j) {
            unsigned short h = bf16_rne(a8[j]);
            ahi[kc][j] = (short)h;
            alo[kc][j] = (short)bf16_rne(a8[j] - bf16f(h));
        }
    }

    // 8 column fragments x 4 k-chunks x 3 MFMA (bf16x3).
    const int orow = row0 + (l >> 4) * 4;
    #pragma unroll
    for (int cf = 0; cf < 8; ++cf) {
        int c = cf * 16 + (l & 15);
        f32x4 acc = {0.f, 0.f, 0.f, 0.f};
        #pragma unroll
        for (int kc = 0; kc < 4; ++kc) {
            int k0 = kc * 32 + koff;
            int byte = (c * 256 + k0 * 2) ^ ((c & 7) << 4);
            short8v bh = *reinterpret_cast<const short8v*>(&Wt[0][byte >> 1]);
            short8v bl = *reinterpret_cast<const short8v*>(&Wt[1][byte >> 1]);
            acc = __builtin_amdgcn_mfma_f32_16x16x32_bf16(ahi[kc], bh, acc, 0, 0, 0);
            acc = __builtin_amdgcn_mfma_f32_16x16x32_bf16(ahi[kc], bl, acc, 0, 0, 0);
            acc = __builtin_amdgcn_mfma_f32_16x16x32_bf16(alo[kc], bh, acc, 0, 0, 0);
        }
        float bb = bias[c];
        #pragma unroll
        for (int j = 0; j < 4; ++j) {
            int r = orow + j;
            if (r < n) io[(size_t)r * 128 + c] = fmaxf(acc[j] + bb, 0.f);
        }
    }
}

static inline size_t align256(size_t v) { return (v + 255) & ~(size_t)255; }

extern "C" void kernel_launch(void* const* d_in, const int* in_sizes, int n_in,
                              void* d_out, int out_size, void* d_ws, size_t ws_size,
                              hipStream_t stream) {
    const float* x = (const float*)d_in[0];
    const int* ei = (const int*)d_in[1];        // harness: integer -> int32
    const float* w = (const float*)d_in[2];
    const float* W = (const float*)d_in[3];
    const float* b = (const float*)d_in[4];
    float* out = (float*)d_out;

    const int N = in_sizes[0] / 128;
    const int E = in_sizes[2];
    const int* row = ei;       // source
    const int* col = ei + E;   // target

    const int nScan = (N + 1023) / 1024;   // 98 for N=100000

    // Workspace partition, 256B-aligned regions; xbf2 last (optional).
    char* base = (char*)d_ws;
    size_t off = 0;
    unsigned long long* packed = (unsigned long long*)(base + off);
    off = align256(off + (size_t)N * 8);
    float* dinv = (float*)(base + off);         off = align256(off + (size_t)N * 4);
    int* cursor = (int*)(base + off);           off = align256(off + (size_t)N * 4);
    int* offs = (int*)(base + off);             off = align256(off + ((size_t)N + 1) * 4);
    int* blockSums = (int*)(base + off);        off = align256(off + 1024 * 4);
    int2* csr = (int2*)(base + off);            off = align256(off + (size_t)E * 8);
    unsigned int* xbf2 = (unsigned int*)(base + off);
    size_t need_bf16 = off + (size_t)N * 64 * 4;
    const bool use_bf16 = (ws_size >= need_bf16);

    const int B = 256;
    const int nx8 = (N * 128) / 8;   // 8 fp32 -> 4 packed bf16x2 per thread

    init_kernel<<<(N + B - 1) / B, B, 0, stream>>>(packed, cursor, N);
    if (use_bf16) {
        int nt = (E > nx8) ? E : nx8;
        hist_cvt_kernel<<<(nt + B - 1) / B, B, 0, stream>>>(col, w, packed, x, xbf2, E, nx8);
    } else {
        edge_hist<<<(E + B - 1) / B, B, 0, stream>>>(col, w, packed, E);
    }
    scan1_kernel<<<nScan, 256, 0, stream>>>(packed, dinv, offs, blockSums, N);
    scan2_kernel<<<1, 1024, 0, stream>>>(blockSums, nScan);
    scan3_kernel<<<nScan, 256, 0, stream>>>(offs, blockSums, N, E);
    scatter_kernel<<<(E + B - 1) / B, B, 0, stream>>>(row, col, w, dinv, offs, cursor,
                                                      csr, E);
    if (use_bf16) {
        agg_kernel_bf16<<<(N + 3) / 4, 256, 0, stream>>>(xbf2, dinv, offs, csr, out, N);
    } else {
        agg_kernel_f32<<<(N + 3) / 4, 256, 0, stream>>>(x, dinv, offs, csr, out, N);
    }
    // out = relu(out @ W + b), in-place MFMA (wave-private 16-row slabs)
    const int nSlabBlocks = (N + 63) / 64;     // 4 slabs of 16 rows per block
    gemm_mfma<<<nSlabBlocks, 256, 0, stream>>>(W, b, out, N);
}

// Round 9
// 251.660 us; speedup vs baseline: 2.4371x; 1.2017x over previous
//
#include <hip/hip_runtime.h>

// ---------------------------------------------------------------------------
// GCNConv + ReLU, aggregate-then-transform (GCN is linear before the GEMM):
//   deg[c]  = 1 + sum_{e: col[e]=c} w[e]
//   dinv    = rsqrt(deg)
//   agg[c]  = dinv[c]^2 * x[c] + sum_{e: col[e]=c} (dinv[row]*w*dinv[c]) * x[row]
//   out     = relu(agg @ W + b)
// R4: packed 64-bit hist atomic. R5: bf16 gathers. R6: 8-way ILP in agg.
// R7: MFMA bf16x3 GEMM (ah@Wh + ah@Wl + al@Wh ~ fp32 accuracy).
// R8: (a) W hi/lo split ONCE to global transposed bf16 planes; GEMM reads
//     B-frags from L2 -> no LDS, no 25.6M bank conflicts, no redundant staging.
//     (b) hist atomic's RETURN VALUE (old count) = edge's rank in its bucket;
//     scatter uses offs[c]+rank[e] -> zero atomics in scatter.
// ---------------------------------------------------------------------------

typedef __attribute__((ext_vector_type(8))) short short8v;   // 8 bf16 (4 VGPR)
typedef __attribute__((ext_vector_type(4))) float f32x4;

static __device__ __forceinline__ float fix2float(unsigned int v) {
    return (float)v * 5.9604644775390625e-8f;   // * 2^-24
}

static __device__ __forceinline__ unsigned short bf16_rne(float f) {
    unsigned int u = __float_as_uint(f);
    u += 0x7FFFu + ((u >> 16) & 1u);
    return (unsigned short)(u >> 16);
}

static __device__ __forceinline__ float bf16f(unsigned short h) {
    return __uint_as_float((unsigned int)h << 16);
}

// fp32 bits -> bf16 (RNE), packed pair (lo element in low 16 bits)
static __device__ __forceinline__ unsigned int pack_bf2(unsigned int lo, unsigned int hi) {
    unsigned int l = (lo + 0x7FFFu + ((lo >> 16) & 1u)) >> 16;
    unsigned int h = (hi + 0x7FFFu + ((hi >> 16) & 1u)) >> 16;
    return l | (h << 16);
}

static __device__ __forceinline__ float2 bf2_to_f2(unsigned int u) {
    union { unsigned int i; float f; } a, b;
    a.i = u << 16;
    b.i = u & 0xFFFF0000u;
    return make_float2(a.f, b.f);
}

__global__ void init_kernel(unsigned long long* __restrict__ packed,
                            int* __restrict__ cursor, int n) {
    int i = blockIdx.x * blockDim.x + threadIdx.x;
    if (i < n) {
        packed[i] = (unsigned long long)(1u << 24);  // deg = 1.0 (self-loop), count = 0
        cursor[i] = 0;
    }
}

// W[k][c] fp32 -> transposed bf16 hi/lo planes Whi[c][k], Wlo[c][k]. 16K elems.
__global__ void wsplit_kernel(const float* __restrict__ W,
                              unsigned short* __restrict__ Whi,
                              unsigned short* __restrict__ Wlo) {
    int t = blockIdx.x * blockDim.x + threadIdx.x;   // 0..16383
    int k = t >> 7;
    int c = t & 127;
    float v = W[k * 128 + c];
    unsigned short h = bf16_rne(v);
    unsigned short l = bf16_rne(v - bf16f(h));
    Whi[c * 128 + k] = h;
    Wlo[c * 128 + k] = l;
}

// Fused: per-edge degree histogram (atomic pipe; old count -> rank) +
// x -> bf16 conversion (read pipe). Thread t: edge t and x dwords [8t, 8t+8).
__global__ void hist_cvt_kernel(const int* __restrict__ col,
                                const float* __restrict__ w,
                                unsigned long long* __restrict__ packed,
                                unsigned short* __restrict__ rank,   // may be null
                                const float* __restrict__ x,
                                unsigned int* __restrict__ xbf2,     // may be null
                                int E, int nx8) {
    int t = blockIdx.x * blockDim.x + threadIdx.x;
    if (xbf2 && t < nx8) {
        const uint4* xin = reinterpret_cast<const uint4*>(x);
        uint4 a = xin[t * 2];
        uint4 b = xin[t * 2 + 1];
        uint4 o;
        o.x = pack_bf2(a.x, a.y);
        o.y = pack_bf2(a.z, a.w);
        o.z = pack_bf2(b.x, b.y);
        o.w = pack_bf2(b.z, b.w);
        reinterpret_cast<uint4*>(xbf2)[t] = o;
    }
    if (t < E) {
        unsigned int fx = (unsigned int)(w[t] * 16777216.0f);  // w in [0,1): < 2^24
        unsigned long long old =
            atomicAdd(&packed[col[t]], (1ULL << 32) | (unsigned long long)fx);
        if (rank) rank[t] = (unsigned short)(old >> 32);
    }
}

// Block-local exclusive scan of 1024-element chunks: counts = packed.hi -> offs
// (partial) + blockSums; fused dinv[i] = rsqrt(packed.lo * 2^-24).
__launch_bounds__(256)
__global__ void scan1_kernel(const unsigned long long* __restrict__ packed,
                             float* __restrict__ dinv,
                             int* __restrict__ offs, int* __restrict__ blockSums, int n) {
    __shared__ int waveSums[4];
    const int tid = threadIdx.x;
    const int lane = tid & 63;
    const int wv = tid >> 6;
    const int base = blockIdx.x * 1024 + tid * 4;

    int c0 = 0, c1 = 0, c2 = 0, c3 = 0;
    if (base + 3 < n) {
        unsigned long long p0 = packed[base];
        unsigned long long p1 = packed[base + 1];
        unsigned long long p2 = packed[base + 2];
        unsigned long long p3 = packed[base + 3];
        c0 = (int)(p0 >> 32); c1 = (int)(p1 >> 32);
        c2 = (int)(p2 >> 32); c3 = (int)(p3 >> 32);
        float4 d;
        d.x = rsqrtf(fix2float((unsigned int)p0));
        d.y = rsqrtf(fix2float((unsigned int)p1));
        d.z = rsqrtf(fix2float((unsigned int)p2));
        d.w = rsqrtf(fix2float((unsigned int)p3));
        *reinterpret_cast<float4*>(&dinv[base]) = d;
    } else {
        for (int t = 0; t < 4; ++t) {
            if (base + t < n) {
                unsigned long long p = packed[base + t];
                int cv = (int)(p >> 32);
                if (t == 0) c0 = cv; else if (t == 1) c1 = cv;
                else if (t == 2) c2 = cv;  else c3 = cv;
                dinv[base + t] = rsqrtf(fix2float((unsigned int)p));
            }
        }
    }
    int s1 = c0 + c1, s2 = s1 + c2, s3 = s2 + c3;

    int incl = s3;
    #pragma unroll
    for (int off = 1; off < 64; off <<= 1) {
        int v = __shfl_up(incl, off);
        if (lane >= off) incl += v;
    }
    if (lane == 63) waveSums[wv] = incl;
    __syncthreads();
    if (tid == 0) {
        int a = 0;
        #pragma unroll
        for (int i = 0; i < 4; ++i) { int t = waveSums[i]; waveSums[i] = a; a += t; }
        blockSums[blockIdx.x] = a;
    }
    __syncthreads();

    int ex = waveSums[wv] + (incl - s3);
    if (base + 3 < n) {
        int4 o;
        o.x = ex; o.y = ex + c0; o.z = ex + s1; o.w = ex + s2;
        *reinterpret_cast<int4*>(&offs[base]) = o;
    } else {
        if (base     < n) offs[base]     = ex;
        if (base + 1 < n) offs[base + 1] = ex + c0;
        if (base + 2 < n) offs[base + 2] = ex + s1;
    }
}

__global__ void scan2_kernel(int* __restrict__ blockSums, int nb) {
    __shared__ int lds[1024];
    int tid = threadIdx.x;
    if (tid < nb) lds[tid] = blockSums[tid];
    __syncthreads();
    if (tid == 0) {
        int a = 0;
        for (int i = 0; i < nb; ++i) { int t = lds[i]; lds[i] = a; a += t; }
    }
    __syncthreads();
    if (tid < nb) blockSums[tid] = lds[tid];
}

__launch_bounds__(256)
__global__ void scan3_kernel(int* __restrict__ offs, const int* __restrict__ blockSums,
                             int n, int total) {
    int i = (blockIdx.x * 256 + threadIdx.x) * 4;
    int bs = blockSums[blockIdx.x];
    if (i + 3 < n) {
        int4 v = *reinterpret_cast<const int4*>(&offs[i]);
        v.x += bs; v.y += bs; v.z += bs; v.w += bs;
        *reinterpret_cast<int4*>(&offs[i]) = v;
    } else {
        if (i     < n) offs[i]     += bs;
        if (i + 1 < n) offs[i + 1] += bs;
        if (i + 2 < n) offs[i + 2] += bs;
    }
    if (blockIdx.x == 0 && threadIdx.x == 0) offs[n] = total;
}

// Atomic-free scatter: position = offs[col] + rank (captured in hist).
__global__ void scatter_rank_kernel(const int* __restrict__ row,
                                    const int* __restrict__ col,
                                    const float* __restrict__ w,
                                    const float* __restrict__ dinv,
                                    const int* __restrict__ offs,
                                    const unsigned short* __restrict__ rank,
                                    int2* __restrict__ csr, int E) {
    int e = blockIdx.x * blockDim.x + threadIdx.x;
    if (e < E) {
        int r = row[e];
        int c = col[e];
        float nw = dinv[r] * w[e] * dinv[c];
        int p = offs[c] + (int)rank[e];
        csr[p] = make_int2(r, __float_as_int(nw));   // one 8B store, no atomic
    }
}

// Fallback scatter with cursor atomics (ws too small for rank).
__global__ void scatter_kernel(const int* __restrict__ row,
                               const int* __restrict__ col,
                               const float* __restrict__ w,
                               const float* __restrict__ dinv,
                               const int* __restrict__ offs,
                               int* __restrict__ cursor,
                               int2* __restrict__ csr, int E) {
    int e = blockIdx.x * blockDim.x + threadIdx.x;
    if (e < E) {
        int r = row[e];
        int c = col[e];
        float nw = dinv[r] * w[e] * dinv[c];
        int p = offs[c] + atomicAdd(&cursor[c], 1);
        csr[p] = make_int2(r, __float_as_int(nw));
    }
}

// One wave per node, bf16 gathers, 8-way ILP: lane owns channels {2l, 2l+1}.
__launch_bounds__(256)
__global__ void agg_kernel_bf16(const unsigned int* __restrict__ xbf2,
                                const float* __restrict__ dinv,
                                const int* __restrict__ offs, const int2* __restrict__ csr,
                                float* __restrict__ aggOut, int n) {
    int wid = (blockIdx.x * blockDim.x + threadIdx.x) >> 6;
    int lane = threadIdx.x & 63;
    if (wid >= n) return;

    float di = dinv[wid];
    float2 xi = bf2_to_f2(xbf2[(size_t)wid * 64 + lane]);
    float sw = di * di;   // self-loop: dinv^2 * 1.0
    float ax0 = sw * xi.x, ay0 = sw * xi.y;   // two independent acc pairs
    float ax1 = 0.f,       ay1 = 0.f;

    int s = offs[wid];
    int e = offs[wid + 1];
    int j = s;

    // 8-way: 8 independent gathers in flight per wave
    for (; j + 8 <= e; j += 8) {
        int2 m0 = csr[j + 0]; int2 m1 = csr[j + 1];
        int2 m2 = csr[j + 2]; int2 m3 = csr[j + 3];
        int2 m4 = csr[j + 4]; int2 m5 = csr[j + 5];
        int2 m6 = csr[j + 6]; int2 m7 = csr[j + 7];
        unsigned int v0 = xbf2[(size_t)m0.x * 64 + lane];
        unsigned int v1 = xbf2[(size_t)m1.x * 64 + lane];
        unsigned int v2 = xbf2[(size_t)m2.x * 64 + lane];
        unsigned int v3 = xbf2[(size_t)m3.x * 64 + lane];
        unsigned int v4 = xbf2[(size_t)m4.x * 64 + lane];
        unsigned int v5 = xbf2[(size_t)m5.x * 64 + lane];
        unsigned int v6 = xbf2[(size_t)m6.x * 64 + lane];
        unsigned int v7 = xbf2[(size_t)m7.x * 64 + lane];
        float2 f0 = bf2_to_f2(v0); float2 f1 = bf2_to_f2(v1);
        float2 f2 = bf2_to_f2(v2); float2 f3 = bf2_to_f2(v3);
        float2 f4 = bf2_to_f2(v4); float2 f5 = bf2_to_f2(v5);
        float2 f6 = bf2_to_f2(v6); float2 f7 = bf2_to_f2(v7);
        float w0 = __int_as_float(m0.y); float w1 = __int_as_float(m1.y);
        float w2 = __int_as_float(m2.y); float w3 = __int_as_float(m3.y);
        float w4 = __int_as_float(m4.y); float w5 = __int_as_float(m5.y);
        float w6 = __int_as_float(m6.y); float w7 = __int_as_float(m7.y);
        ax0 += w0 * f0.x; ay0 += w0 * f0.y;
        ax1 += w1 * f1.x; ay1 += w1 * f1.y;
        ax0 += w2 * f2.x; ay0 += w2 * f2.y;
        ax1 += w3 * f3.x; ay1 += w3 * f3.y;
        ax0 += w4 * f4.x; ay0 += w4 * f4.y;
        ax1 += w5 * f5.x; ay1 += w5 * f5.y;
        ax0 += w6 * f6.x; ay0 += w6 * f6.y;
        ax1 += w7 * f7.x; ay1 += w7 * f7.y;
    }
    // 2-way
    for (; j + 2 <= e; j += 2) {
        int2 m0 = csr[j + 0]; int2 m1 = csr[j + 1];
        unsigned int v0 = xbf2[(size_t)m0.x * 64 + lane];
        unsigned int v1 = xbf2[(size_t)m1.x * 64 + lane];
        float2 f0 = bf2_to_f2(v0); float2 f1 = bf2_to_f2(v1);
        float w0 = __int_as_float(m0.y); float w1 = __int_as_float(m1.y);
        ax0 += w0 * f0.x; ay0 += w0 * f0.y;
        ax1 += w1 * f1.x; ay1 += w1 * f1.y;
    }
    // scalar tail
    for (; j < e; ++j) {
        int2 m = csr[j];
        float2 f = bf2_to_f2(xbf2[(size_t)m.x * 64 + lane]);
        float wn = __int_as_float(m.y);
        ax0 += wn * f.x; ay0 += wn * f.y;
    }

    float2 acc;
    acc.x = ax0 + ax1;
    acc.y = ay0 + ay1;
    *reinterpret_cast<float2*>(&aggOut[(size_t)wid * 128 + lane * 2]) = acc;
}

// fp32 fallback (ws too small for xbf2), same ILP structure
__launch_bounds__(256)
__global__ void agg_kernel_f32(const float* __restrict__ x, const float* __restrict__ dinv,
                               const int* __restrict__ offs, const int2* __restrict__ csr,
                               float* __restrict__ aggOut, int n) {
    int wid = (blockIdx.x * blockDim.x + threadIdx.x) >> 6;
    int lane = threadIdx.x & 63;
    if (wid >= n) return;

    float di = dinv[wid];
    float2 xi = *reinterpret_cast<const float2*>(&x[(size_t)wid * 128 + lane * 2]);
    float sw = di * di;
    float ax0 = sw * xi.x, ay0 = sw * xi.y;
    float ax1 = 0.f,       ay1 = 0.f;

    int s = offs[wid];
    int e = offs[wid + 1];
    int j = s;
    for (; j + 4 <= e; j += 4) {
        int2 m0 = csr[j + 0]; int2 m1 = csr[j + 1];
        int2 m2 = csr[j + 2]; int2 m3 = csr[j + 3];
        float2 f0 = *reinterpret_cast<const float2*>(&x[(size_t)m0.x * 128 + lane * 2]);
        float2 f1 = *reinterpret_cast<const float2*>(&x[(size_t)m1.x * 128 + lane * 2]);
        float2 f2 = *reinterpret_cast<const float2*>(&x[(size_t)m2.x * 128 + lane * 2]);
        float2 f3 = *reinterpret_cast<const float2*>(&x[(size_t)m3.x * 128 + lane * 2]);
        float w0 = __int_as_float(m0.y); float w1 = __int_as_float(m1.y);
        float w2 = __int_as_float(m2.y); float w3 = __int_as_float(m3.y);
        ax0 += w0 * f0.x; ay0 += w0 * f0.y;
        ax1 += w1 * f1.x; ay1 += w1 * f1.y;
        ax0 += w2 * f2.x; ay0 += w2 * f2.y;
        ax1 += w3 * f3.x; ay1 += w3 * f3.y;
    }
    for (; j < e; ++j) {
        int2 m = csr[j];
        float wn = __int_as_float(m.y);
        float2 f = *reinterpret_cast<const float2*>(&x[(size_t)m.x * 128 + lane * 2]);
        ax0 += wn * f.x; ay0 += wn * f.y;
    }
    float2 acc;
    acc.x = ax0 + ax1;
    acc.y = ay0 + ay1;
    *reinterpret_cast<float2*>(&aggOut[(size_t)wid * 128 + lane * 2]) = acc;
}

// ---------------------------------------------------------------------------
// MFMA GEMM, in-place on io: io = relu(io @ W + b), bf16x3, NO LDS.
// B-fragments read directly from global transposed bf16 planes (L2-resident).
// Block: 4 waves x 16-row slabs; wave reads its rows fully before writing.
// ---------------------------------------------------------------------------
__launch_bounds__(256)
__global__ void gemm_mfma2(const unsigned short* __restrict__ Whi,
                           const unsigned short* __restrict__ Wlo,
                           const float* __restrict__ bias,
                           float* __restrict__ io, int n) {
    const int tid = threadIdx.x;
    const int wv = tid >> 6;
    const int l = tid & 63;
    const int row0 = (blockIdx.x * 4 + wv) * 16;   // this wave's 16-row slab
    if (row0 >= n) return;

    const int arow = row0 + (l & 15);
    const int koff = (l >> 4) * 8;                 // k sub-offset within 32-chunk
    const bool rok = arow < n;

    // Load A slab fp32, split into hi/lo bf16 fragments (registers only).
    short8v ahi[4], alo[4];
    #pragma unroll
    for (int kc = 0; kc < 4; ++kc) {
        float4 p0 = make_float4(0.f, 0.f, 0.f, 0.f);
        float4 p1 = p0;
        if (rok) {
            const float* src = io + (size_t)arow * 128 + kc * 32 + koff;
            p0 = *reinterpret_cast<const float4*>(src);
            p1 = *reinterpret_cast<const float4*>(src + 4);
        }
        float a8[8] = {p0.x, p0.y, p0.z, p0.w, p1.x, p1.y, p1.z, p1.w};
        #pragma unroll
        for (int j = 0; j < 8; ++j) {
            unsigned short h = bf16_rne(a8[j]);
            ahi[kc][j] = (short)h;
            alo[kc][j] = (short)bf16_rne(a8[j] - bf16f(h));
        }
    }

    const int orow = row0 + (l >> 4) * 4;
    const int cbase = l & 15;
    #pragma unroll
    for (int cf = 0; cf < 8; ++cf) {
        int c = cf * 16 + cbase;
        const unsigned short* ph = Whi + c * 128 + koff;
        const unsigned short* pl = Wlo + c * 128 + koff;
        f32x4 acc = {0.f, 0.f, 0.f, 0.f};
        #pragma unroll
        for (int kc = 0; kc < 4; ++kc) {
            short8v bh = *reinterpret_cast<const short8v*>(ph + kc * 32);
            short8v bl = *reinterpret_cast<const short8v*>(pl + kc * 32);
            acc = __builtin_amdgcn_mfma_f32_16x16x32_bf16(ahi[kc], bh, acc, 0, 0, 0);
            acc = __builtin_amdgcn_mfma_f32_16x16x32_bf16(ahi[kc], bl, acc, 0, 0, 0);
            acc = __builtin_amdgcn_mfma_f32_16x16x32_bf16(alo[kc], bh, acc, 0, 0, 0);
        }
        float bb = bias[c];
        #pragma unroll
        for (int j = 0; j < 4; ++j) {
            int r = orow + j;
            if (r < n) io[(size_t)r * 128 + c] = fmaxf(acc[j] + bb, 0.f);
        }
    }
}

static inline size_t align256(size_t v) { return (v + 255) & ~(size_t)255; }

extern "C" void kernel_launch(void* const* d_in, const int* in_sizes, int n_in,
                              void* d_out, int out_size, void* d_ws, size_t ws_size,
                              hipStream_t stream) {
    const float* x = (const float*)d_in[0];
    const int* ei = (const int*)d_in[1];        // harness: integer -> int32
    const float* w = (const float*)d_in[2];
    const float* W = (const float*)d_in[3];
    const float* b = (const float*)d_in[4];
    float* out = (float*)d_out;

    const int N = in_sizes[0] / 128;
    const int E = in_sizes[2];
    const int* row = ei;       // source
    const int* col = ei + E;   // target

    const int nScan = (N + 1023) / 1024;   // 98 for N=100000

    // Workspace: mandatory, then tier1 = xbf2, tier2 = rank.
    char* base = (char*)d_ws;
    size_t off = 0;
    unsigned long long* packed = (unsigned long long*)(base + off);
    off = align256(off + (size_t)N * 8);
    float* dinv = (float*)(base + off);         off = align256(off + (size_t)N * 4);
    int* cursor = (int*)(base + off);           off = align256(off + (size_t)N * 4);
    int* offs = (int*)(base + off);             off = align256(off + ((size_t)N + 1) * 4);
    int* blockSums = (int*)(base + off);        off = align256(off + 1024 * 4);
    int2* csr = (int2*)(base + off);            off = align256(off + (size_t)E * 8);
    unsigned short* Whi = (unsigned short*)(base + off);
    off = align256(off + (size_t)128 * 128 * 2);
    unsigned short* Wlo = (unsigned short*)(base + off);
    off = align256(off + (size_t)128 * 128 * 2);
    unsigned int* xbf2 = (unsigned int*)(base + off);
    size_t need_bf16 = off + (size_t)N * 64 * 4;
    const bool use_bf16 = (ws_size >= need_bf16);
    unsigned short* rank = (unsigned short*)(base + align256(need_bf16));
    size_t need_rank = align256(need_bf16) + (size_t)E * 2;
    const bool use_rank = (ws_size >= need_rank);

    const int B = 256;
    const int nx8 = (N * 128) / 8;   // 8 fp32 -> 4 packed bf16x2 per thread

    init_kernel<<<(N + B - 1) / B, B, 0, stream>>>(packed, cursor, N);
    wsplit_kernel<<<64, 256, 0, stream>>>(W, Whi, Wlo);
    {
        int nt = use_bf16 ? ((E > nx8) ? E : nx8) : E;
        hist_cvt_kernel<<<(nt + B - 1) / B, B, 0, stream>>>(
            col, w, packed, use_rank ? rank : nullptr,
            x, use_bf16 ? xbf2 : nullptr, E, nx8);
    }
    scan1_kernel<<<nScan, 256, 0, stream>>>(packed, dinv, offs, blockSums, N);
    scan2_kernel<<<1, 1024, 0, stream>>>(blockSums, nScan);
    scan3_kernel<<<nScan, 256, 0, stream>>>(offs, blockSums, N, E);
    if (use_rank) {
        scatter_rank_kernel<<<(E + B - 1) / B, B, 0, stream>>>(row, col, w, dinv, offs,
                                                               rank, csr, E);
    } else {
        scatter_kernel<<<(E + B - 1) / B, B, 0, stream>>>(row, col, w, dinv, offs,
                                                          cursor, csr, E);
    }
    if (use_bf16) {
        agg_kernel_bf16<<<(N + 3) / 4, 256, 0, stream>>>(xbf2, dinv, offs, csr, out, N);
    } else {
        agg_kernel_f32<<<(N + 3) / 4, 256, 0, stream>>>(x, dinv, offs, csr, out, N);
    }
    // out = relu(out @ W + b), in-place MFMA, B-frags from global (no LDS)
    const int nSlabBlocks = (N + 63) / 64;
    gemm_mfma2<<<nSlabBlocks, 256, 0, stream>>>(Whi, Wlo, b, out, N);
}

// Round 10
// 235.366 us; speedup vs baseline: 2.6059x; 1.0692x over previous
//
#include <hip/hip_runtime.h>

// ---------------------------------------------------------------------------
// GCNConv + ReLU, aggregate-then-transform (GCN is linear before the GEMM):
//   deg[c]  = 1 + sum_{e: col[e]=c} w[e];  dinv = rsqrt(deg)
//   agg[c]  = dinv[c]^2*x[c] + sum_{e: col[e]=c} (dinv[row]*w*dinv[c]) * x[row]
//   out     = relu(agg @ W + b)
// R5: bf16 gathers. R6: 8-way ILP agg. R7/R8: bf16x3 MFMA GEMM, no LDS.
// R9: two-level bucket sort (64-node buckets, nb=1563):
//     - coarse LDS hist + per-(block,bin) merge: 1.6M global atomics -> ~200k
//     - bucket_finalize computes deg/count via LDS atomics (global hist GONE)
//     - csr written within 8KB L2-resident regions (no 64B/8B write amp)
//     - csr carries (r, w); agg applies dinv[r]*dinv[c] on the fly
// ---------------------------------------------------------------------------

#define BSHIFT 6
#define BNODES 64

typedef __attribute__((ext_vector_type(8))) short short8v;   // 8 bf16 (4 VGPR)
typedef __attribute__((ext_vector_type(4))) float f32x4;

static __device__ __forceinline__ unsigned short bf16_rne(float f) {
    unsigned int u = __float_as_uint(f);
    u += 0x7FFFu + ((u >> 16) & 1u);
    return (unsigned short)(u >> 16);
}

static __device__ __forceinline__ float bf16f(unsigned short h) {
    return __uint_as_float((unsigned int)h << 16);
}

static __device__ __forceinline__ unsigned int pack_bf2(unsigned int lo, unsigned int hi) {
    unsigned int l = (lo + 0x7FFFu + ((lo >> 16) & 1u)) >> 16;
    unsigned int h = (hi + 0x7FFFu + ((hi >> 16) & 1u)) >> 16;
    return l | (h << 16);
}

static __device__ __forceinline__ float2 bf2_to_f2(unsigned int u) {
    union { unsigned int i; float f; } a, b;
    a.i = u << 16;
    b.i = u & 0xFFFF0000u;
    return make_float2(a.f, b.f);
}

// W[k][c] fp32 -> transposed bf16 hi/lo planes Whi[c][k], Wlo[c][k].
__global__ void wsplit_kernel(const float* __restrict__ W,
                              unsigned short* __restrict__ Whi,
                              unsigned short* __restrict__ Wlo) {
    int t = blockIdx.x * blockDim.x + threadIdx.x;   // 0..16383
    int k = t >> 7;
    int c = t & 127;
    float v = W[k * 128 + c];
    unsigned short h = bf16_rne(v);
    unsigned short l = bf16_rne(v - bf16f(h));
    Whi[c * 128 + k] = h;
    Wlo[c * 128 + k] = l;
}

// x -> packed bf16 pairs, grid-strided.
__global__ void cvt_kernel(const float* __restrict__ x,
                           unsigned int* __restrict__ xbf2, int nx8) {
    int stride = gridDim.x * blockDim.x;
    for (int t = blockIdx.x * blockDim.x + threadIdx.x; t < nx8; t += stride) {
        const uint4* xin = reinterpret_cast<const uint4*>(x);
        uint4 a = xin[t * 2];
        uint4 b = xin[t * 2 + 1];
        uint4 o;
        o.x = pack_bf2(a.x, a.y);
        o.y = pack_bf2(a.z, a.w);
        o.z = pack_bf2(b.x, b.y);
        o.w = pack_bf2(b.z, b.w);
        reinterpret_cast<uint4*>(xbf2)[t] = o;
    }
}

// Per-block LDS histogram over nb coarse buckets, then one global atomic per
// (block, nonempty bin).
__global__ void coarse_hist(const int* __restrict__ col,
                            unsigned int* __restrict__ coarseCnt,
                            int E, int epb, int nb) {
    extern __shared__ unsigned int lh[];
    for (int i = threadIdx.x; i < nb; i += blockDim.x) lh[i] = 0;
    __syncthreads();
    int s = blockIdx.x * epb;
    int e = s + epb; if (e > E) e = E;
    for (int i = s + threadIdx.x; i < e; i += blockDim.x)
        atomicAdd(&lh[((unsigned)col[i]) >> BSHIFT], 1u);
    __syncthreads();
    for (int i = threadIdx.x; i < nb; i += blockDim.x) {
        unsigned v = lh[i];
        if (v) atomicAdd(&coarseCnt[i], v);
    }
}

// Exclusive scan over nb (~1563) coarse counts; writes offsE[0..nb] and a
// working copy into cursor[0..nb).
__global__ void coarse_scan(const unsigned int* __restrict__ cnt,
                            unsigned int* __restrict__ offsE,
                            unsigned int* __restrict__ cursor, int nb) {
    __shared__ unsigned int wsum[4];
    __shared__ unsigned int totalSh;
    const int tid = threadIdx.x;       // 256 threads
    const int lane = tid & 63, wv = tid >> 6;
    int chunk = (nb + 255) / 256;
    int s = tid * chunk;
    int e = s + chunk;
    if (s > nb) s = nb;
    if (e > nb) e = nb;
    unsigned sum = 0;
    for (int i = s; i < e; ++i) sum += cnt[i];
    unsigned incl = sum;
    #pragma unroll
    for (int off = 1; off < 64; off <<= 1) {
        unsigned v = __shfl_up(incl, off);
        if (lane >= off) incl += v;
    }
    if (lane == 63) wsum[wv] = incl;
    __syncthreads();
    if (tid == 0) {
        unsigned a = 0;
        #pragma unroll
        for (int i = 0; i < 4; ++i) { unsigned t = wsum[i]; wsum[i] = a; a += t; }
        totalSh = a;
    }
    __syncthreads();
    unsigned ex = wsum[wv] + (incl - sum);
    for (int i = s; i < e; ++i) {
        unsigned c = cnt[i];
        offsE[i] = ex;
        cursor[i] = ex;
        ex += c;
    }
    if (tid == 0) offsE[nb] = totalSh;
}

// Group edges by coarse bucket: per-block LDS hist -> one reservation atomic
// per (block,bin) -> grouped writes. Entry packs {r | cLow<<24, w bits}.
__global__ void bucket_scatter(const int* __restrict__ row, const int* __restrict__ col,
                               const float* __restrict__ w,
                               unsigned int* __restrict__ cursor,
                               int2* __restrict__ bucketed, int E, int epb, int nb) {
    extern __shared__ unsigned int lds[];
    unsigned int* lh = lds;
    unsigned int* lbase = lds + nb;
    unsigned int* lpos = lds + 2 * nb;
    for (int i = threadIdx.x; i < nb; i += blockDim.x) { lh[i] = 0; lpos[i] = 0; }
    __syncthreads();
    int s = blockIdx.x * epb;
    int e = s + epb; if (e > E) e = E;
    for (int i = s + threadIdx.x; i < e; i += blockDim.x)
        atomicAdd(&lh[((unsigned)col[i]) >> BSHIFT], 1u);
    __syncthreads();
    for (int i = threadIdx.x; i < nb; i += blockDim.x) {
        unsigned v = lh[i];
        if (v) lbase[i] = atomicAdd(&cursor[i], v);
    }
    __syncthreads();
    for (int i = s + threadIdx.x; i < e; i += blockDim.x) {
        int c = col[i];
        int bk = ((unsigned)c) >> BSHIFT;
        unsigned p = lbase[bk] + atomicAdd(&lpos[bk], 1u);
        bucketed[p] = make_int2(row[i] | ((c & (BNODES - 1)) << 24),
                                __float_as_int(w[i]));
    }
}

// One block per bucket: LDS-compute count+weighted degree (packed u64 LDS
// atomics), write dinv/offs sequentially, place csr entries in the bucket's
// contiguous (L2-resident) region.
__launch_bounds__(256)
__global__ void bucket_finalize(const int2* __restrict__ bucketed,
                                const unsigned int* __restrict__ offsE,
                                float* __restrict__ dinv, int* __restrict__ offs,
                                int2* __restrict__ csr, int n, int E) {
    __shared__ unsigned long long pdeg[BNODES];
    __shared__ unsigned int fineEx[BNODES];
    __shared__ unsigned int lcur[BNODES];
    const int b = blockIdx.x, tid = threadIdx.x;
    const int node0 = b << BSHIFT;
    const int nNodes = min(BNODES, n - node0);
    const unsigned s = offsE[b], e = offsE[b + 1];

    if (tid < BNODES) { pdeg[tid] = (1ull << 24); lcur[tid] = 0; }  // deg=1 (self-loop)
    __syncthreads();
    for (unsigned i = s + tid; i < e; i += 256) {
        int2 m = bucketed[i];
        unsigned cl = ((unsigned)m.x) >> 24;
        unsigned fx = (unsigned)(__int_as_float(m.y) * 16777216.0f);
        atomicAdd(&pdeg[cl], (1ull << 32) | (unsigned long long)fx);
    }
    __syncthreads();
    if (tid < BNODES) {   // wave 0 only: 64-lane scan
        unsigned long long p = pdeg[tid];
        unsigned cnt = (unsigned)(p >> 32);
        unsigned incl = cnt;
        #pragma unroll
        for (int off = 1; off < 64; off <<= 1) {
            unsigned v = __shfl_up(incl, off);
            if (tid >= off) incl += v;
        }
        fineEx[tid] = incl - cnt;
        if (tid < nNodes) {
            dinv[node0 + tid] = rsqrtf((float)(unsigned)p * 5.9604644775390625e-8f);
            offs[node0 + tid] = (int)(s + incl - cnt);
        }
    }
    __syncthreads();
    for (unsigned i = s + tid; i < e; i += 256) {
        int2 m = bucketed[i];
        unsigned cl = ((unsigned)m.x) >> 24;
        int r = m.x & 0x00FFFFFF;
        unsigned pos = s + fineEx[cl] + atomicAdd(&lcur[cl], 1u);
        csr[pos] = make_int2(r, m.y);   // (srcRow, w bits)
    }
    if (b == 0 && tid == 0) offs[n] = E;
}

// One wave per node, bf16 gathers, 8-way ILP. csr = (r, w); nw computed here.
__launch_bounds__(256)
__global__ void agg_kernel_bf16(const unsigned int* __restrict__ xbf2,
                                const float* __restrict__ dinv,
                                const int* __restrict__ offs, const int2* __restrict__ csr,
                                float* __restrict__ aggOut, int n) {
    int wid = (blockIdx.x * blockDim.x + threadIdx.x) >> 6;
    int lane = threadIdx.x & 63;
    if (wid >= n) return;

    float di = dinv[wid];
    float2 xi = bf2_to_f2(xbf2[(size_t)wid * 64 + lane]);
    float sw = di * di;   // self-loop: dinv^2 * 1.0
    float ax0 = sw * xi.x, ay0 = sw * xi.y;
    float ax1 = 0.f,       ay1 = 0.f;

    int s = offs[wid];
    int e = offs[wid + 1];
    int j = s;

    for (; j + 8 <= e; j += 8) {
        int2 m0 = csr[j + 0]; int2 m1 = csr[j + 1];
        int2 m2 = csr[j + 2]; int2 m3 = csr[j + 3];
        int2 m4 = csr[j + 4]; int2 m5 = csr[j + 5];
        int2 m6 = csr[j + 6]; int2 m7 = csr[j + 7];
        unsigned int v0 = xbf2[(size_t)m0.x * 64 + lane];
        unsigned int v1 = xbf2[(size_t)m1.x * 64 + lane];
        unsigned int v2 = xbf2[(size_t)m2.x * 64 + lane];
        unsigned int v3 = xbf2[(size_t)m3.x * 64 + lane];
        unsigned int v4 = xbf2[(size_t)m4.x * 64 + lane];
        unsigned int v5 = xbf2[(size_t)m5.x * 64 + lane];
        unsigned int v6 = xbf2[(size_t)m6.x * 64 + lane];
        unsigned int v7 = xbf2[(size_t)m7.x * 64 + lane];
        float dv0 = dinv[m0.x]; float dv1 = dinv[m1.x];
        float dv2 = dinv[m2.x]; float dv3 = dinv[m3.x];
        float dv4 = dinv[m4.x]; float dv5 = dinv[m5.x];
        float dv6 = dinv[m6.x]; float dv7 = dinv[m7.x];
        float2 f0 = bf2_to_f2(v0); float2 f1 = bf2_to_f2(v1);
        float2 f2 = bf2_to_f2(v2); float2 f3 = bf2_to_f2(v3);
        float2 f4 = bf2_to_f2(v4); float2 f5 = bf2_to_f2(v5);
        float2 f6 = bf2_to_f2(v6); float2 f7 = bf2_to_f2(v7);
        float w0 = __int_as_float(m0.y) * dv0 * di;
        float w1 = __int_as_float(m1.y) * dv1 * di;
        float w2 = __int_as_float(m2.y) * dv2 * di;
        float w3 = __int_as_float(m3.y) * dv3 * di;
        float w4 = __int_as_float(m4.y) * dv4 * di;
        float w5 = __int_as_float(m5.y) * dv5 * di;
        float w6 = __int_as_float(m6.y) * dv6 * di;
        float w7 = __int_as_float(m7.y) * dv7 * di;
        ax0 += w0 * f0.x; ay0 += w0 * f0.y;
        ax1 += w1 * f1.x; ay1 += w1 * f1.y;
        ax0 += w2 * f2.x; ay0 += w2 * f2.y;
        ax1 += w3 * f3.x; ay1 += w3 * f3.y;
        ax0 += w4 * f4.x; ay0 += w4 * f4.y;
        ax1 += w5 * f5.x; ay1 += w5 * f5.y;
        ax0 += w6 * f6.x; ay0 += w6 * f6.y;
        ax1 += w7 * f7.x; ay1 += w7 * f7.y;
    }
    for (; j + 2 <= e; j += 2) {
        int2 m0 = csr[j + 0]; int2 m1 = csr[j + 1];
        unsigned int v0 = xbf2[(size_t)m0.x * 64 + lane];
        unsigned int v1 = xbf2[(size_t)m1.x * 64 + lane];
        float w0 = __int_as_float(m0.y) * dinv[m0.x] * di;
        float w1 = __int_as_float(m1.y) * dinv[m1.x] * di;
        float2 f0 = bf2_to_f2(v0); float2 f1 = bf2_to_f2(v1);
        ax0 += w0 * f0.x; ay0 += w0 * f0.y;
        ax1 += w1 * f1.x; ay1 += w1 * f1.y;
    }
    for (; j < e; ++j) {
        int2 m = csr[j];
        float2 f = bf2_to_f2(xbf2[(size_t)m.x * 64 + lane]);
        float wn = __int_as_float(m.y) * dinv[m.x] * di;
        ax0 += wn * f.x; ay0 += wn * f.y;
    }

    float2 acc;
    acc.x = ax0 + ax1;
    acc.y = ay0 + ay1;
    *reinterpret_cast<float2*>(&aggOut[(size_t)wid * 128 + lane * 2]) = acc;
}

// MFMA GEMM, in-place on io: io = relu(io @ W + b), bf16x3, no LDS.
__launch_bounds__(256)
__global__ void gemm_mfma2(const unsigned short* __restrict__ Whi,
                           const unsigned short* __restrict__ Wlo,
                           const float* __restrict__ bias,
                           float* __restrict__ io, int n) {
    const int tid = threadIdx.x;
    const int wv = tid >> 6;
    const int l = tid & 63;
    const int row0 = (blockIdx.x * 4 + wv) * 16;
    if (row0 >= n) return;

    const int arow = row0 + (l & 15);
    const int koff = (l >> 4) * 8;
    const bool rok = arow < n;

    short8v ahi[4], alo[4];
    #pragma unroll
    for (int kc = 0; kc < 4; ++kc) {
        float4 p0 = make_float4(0.f, 0.f, 0.f, 0.f);
        float4 p1 = p0;
        if (rok) {
            const float* src = io + (size_t)arow * 128 + kc * 32 + koff;
            p0 = *reinterpret_cast<const float4*>(src);
            p1 = *reinterpret_cast<const float4*>(src + 4);
        }
        float a8[8] = {p0.x, p0.y, p0.z, p0.w, p1.x, p1.y, p1.z, p1.w};
        #pragma unroll
        for (int j = 0; j < 8; ++j) {
            unsigned short h = bf16_rne(a8[j]);
            ahi[kc][j] = (short)h;
            alo[kc][j] = (short)bf16_rne(a8[j] - bf16f(h));
        }
    }

    const int orow = row0 + (l >> 4) * 4;
    const int cbase = l & 15;
    #pragma unroll
    for (int cf = 0; cf < 8; ++cf) {
        int c = cf * 16 + cbase;
        const unsigned short* ph = Whi + c * 128 + koff;
        const unsigned short* pl = Wlo + c * 128 + koff;
        f32x4 acc = {0.f, 0.f, 0.f, 0.f};
        #pragma unroll
        for (int kc = 0; kc < 4; ++kc) {
            short8v bh = *reinterpret_cast<const short8v*>(ph + kc * 32);
            short8v bl = *reinterpret_cast<const short8v*>(pl + kc * 32);
            acc = __builtin_amdgcn_mfma_f32_16x16x32_bf16(ahi[kc], bh, acc, 0, 0, 0);
            acc = __builtin_amdgcn_mfma_f32_16x16x32_bf16(ahi[kc], bl, acc, 0, 0, 0);
            acc = __builtin_amdgcn_mfma_f32_16x16x32_bf16(alo[kc], bh, acc, 0, 0, 0);
        }
        float bb = bias[c];
        #pragma unroll
        for (int j = 0; j < 4; ++j) {
            int r = orow + j;
            if (r < n) io[(size_t)r * 128 + c] = fmaxf(acc[j] + bb, 0.f);
        }
    }
}

static inline size_t align256(size_t v) { return (v + 255) & ~(size_t)255; }

extern "C" void kernel_launch(void* const* d_in, const int* in_sizes, int n_in,
                              void* d_out, int out_size, void* d_ws, size_t ws_size,
                              hipStream_t stream) {
    const float* x = (const float*)d_in[0];
    const int* ei = (const int*)d_in[1];        // harness: integer -> int32
    const float* w = (const float*)d_in[2];
    const float* W = (const float*)d_in[3];
    const float* b = (const float*)d_in[4];
    float* out = (float*)d_out;

    const int N = in_sizes[0] / 128;
    const int E = in_sizes[2];
    const int* row = ei;       // source
    const int* col = ei + E;   // target

    const int nb = (N + BNODES - 1) / BNODES;   // 1563 coarse buckets

    // Workspace (~39 MB): xbf2 aliases bucketed (dead after bucket_finalize).
    char* base = (char*)d_ws;
    size_t off = 0;
    float* dinv = (float*)(base + off);          off = align256(off + (size_t)N * 4);
    int* offs = (int*)(base + off);              off = align256(off + ((size_t)N + 1) * 4);
    unsigned int* coarseCnt = (unsigned int*)(base + off);
    off = align256(off + (size_t)nb * 4);
    unsigned int* offsE = (unsigned int*)(base + off);
    off = align256(off + ((size_t)nb + 1) * 4);
    unsigned int* cursor = (unsigned int*)(base + off);
    off = align256(off + (size_t)nb * 4);
    unsigned short* Whi = (unsigned short*)(base + off);
    off = align256(off + (size_t)128 * 128 * 2);
    unsigned short* Wlo = (unsigned short*)(base + off);
    off = align256(off + (size_t)128 * 128 * 2);
    int2* csr = (int2*)(base + off);             off = align256(off + (size_t)E * 8);
    int2* bucketed = (int2*)(base + off);                       // E*8
    unsigned int* xbf2 = (unsigned int*)(base + off);           // N*256 (union)

    const int nBS = 128;
    const int epb = (E + nBS - 1) / nBS;
    const int nx8 = (N * 128) / 8;

    hipMemsetAsync(coarseCnt, 0, (size_t)nb * 4, stream);
    wsplit_kernel<<<64, 256, 0, stream>>>(W, Whi, Wlo);
    coarse_hist<<<nBS, 256, nb * 4, stream>>>(col, coarseCnt, E, epb, nb);
    coarse_scan<<<1, 256, 0, stream>>>(coarseCnt, offsE, cursor, nb);
    bucket_scatter<<<nBS, 256, 3 * nb * 4, stream>>>(row, col, w, cursor, bucketed,
                                                     E, epb, nb);
    bucket_finalize<<<nb, 256, 0, stream>>>(bucketed, offsE, dinv, offs, csr, N, E);
    cvt_kernel<<<2048, 256, 0, stream>>>(x, xbf2, nx8);   // overwrites bucketed (dead)
    agg_kernel_bf16<<<(N + 3) / 4, 256, 0, stream>>>(xbf2, dinv, offs, csr, out, N);
    gemm_mfma2<<<(N + 63) / 64, 256, 0, stream>>>(Whi, Wlo, b, out, N);
}

// Round 11
// 198.057 us; speedup vs baseline: 3.0967x; 1.1884x over previous
//
#include <hip/hip_runtime.h>

// ---------------------------------------------------------------------------
// GCNConv + ReLU, aggregate-then-transform (GCN is linear before the GEMM):
//   deg[c]  = 1 + sum_{e: col[e]=c} w[e];  dinv = rsqrt(deg)
//   agg[c]  = dinv[c]^2*x[c] + sum_{e: col[e]=c} (dinv[row]*w*dinv[c]) * x[row]
//   out     = relu(agg @ W + b)
// R5: bf16 gathers. R6: 8-way ILP agg. R7/R8: bf16x3 MFMA GEMM, no LDS.
// R9: two-level bucket sort (64-node buckets).
// R10: bucket_scatter was 4.9%-occupancy latency-bound (128 blks) ->
//  - coarse_hist writes per-(bin,block) counts to histM; hierarchical scan
//    over histM gives every block its exact base -> ZERO global atomics
//  - 256 blocks x 1024 threads for hist/scatter (full chip)
//  - dinv[r] folded into xbf2 at cvt (xbf2 = bf16(x*dinv)) -> agg drops the
//    per-edge random dinv load
// ---------------------------------------------------------------------------

#define BSHIFT 6
#define BNODES 64
#define NBS 256          // blocks for hist/scatter

typedef __attribute__((ext_vector_type(8))) short short8v;   // 8 bf16 (4 VGPR)
typedef __attribute__((ext_vector_type(4))) float f32x4;

static __device__ __forceinline__ unsigned short bf16_rne(float f) {
    unsigned int u = __float_as_uint(f);
    u += 0x7FFFu + ((u >> 16) & 1u);
    return (unsigned short)(u >> 16);
}

static __device__ __forceinline__ float bf16f(unsigned short h) {
    return __uint_as_float((unsigned int)h << 16);
}

static __device__ __forceinline__ unsigned int pack_bf2f(float lo, float hi) {
    unsigned int a = __float_as_uint(lo), b = __float_as_uint(hi);
    a = (a + 0x7FFFu + ((a >> 16) & 1u)) >> 16;
    b = (b + 0x7FFFu + ((b >> 16) & 1u)) >> 16;
    return a | (b << 16);
}

static __device__ __forceinline__ float2 bf2_to_f2(unsigned int u) {
    union { unsigned int i; float f; } a, b;
    a.i = u << 16;
    b.i = u & 0xFFFF0000u;
    return make_float2(a.f, b.f);
}

// W[k][c] fp32 -> transposed bf16 hi/lo planes Whi[c][k], Wlo[c][k].
__global__ void wsplit_kernel(const float* __restrict__ W,
                              unsigned short* __restrict__ Whi,
                              unsigned short* __restrict__ Wlo) {
    int t = blockIdx.x * blockDim.x + threadIdx.x;   // 0..16383
    int k = t >> 7;
    int c = t & 127;
    float v = W[k * 128 + c];
    unsigned short h = bf16_rne(v);
    unsigned short l = bf16_rne(v - bf16f(h));
    Whi[c * 128 + k] = h;
    Wlo[c * 128 + k] = l;
}

// xbf2[node] = bf16(x[node] * dinv[node]), packed pairs. 16 threads per node.
__global__ void cvt_kernel(const float* __restrict__ x, const float* __restrict__ dinv,
                           unsigned int* __restrict__ xbf2, int nx8) {
    int stride = gridDim.x * blockDim.x;
    for (int t = blockIdx.x * blockDim.x + threadIdx.x; t < nx8; t += stride) {
        float di = dinv[t >> 4];
        const float4* xin = reinterpret_cast<const float4*>(x);
        float4 a = xin[t * 2];
        float4 b = xin[t * 2 + 1];
        uint4 o;
        o.x = pack_bf2f(a.x * di, a.y * di);
        o.y = pack_bf2f(a.z * di, a.w * di);
        o.z = pack_bf2f(b.x * di, b.y * di);
        o.w = pack_bf2f(b.z * di, b.w * di);
        reinterpret_cast<uint4*>(xbf2)[t] = o;
    }
}

// Per-block LDS histogram over nb coarse buckets -> histM[bin][blk] (no atomics).
__launch_bounds__(1024)
__global__ void coarse_hist(const int* __restrict__ col,
                            unsigned int* __restrict__ histM,
                            int E, int epb, int nb) {
    extern __shared__ unsigned int lh[];
    for (int i = threadIdx.x; i < nb; i += blockDim.x) lh[i] = 0;
    __syncthreads();
    int s = blockIdx.x * epb;
    int e = s + epb; if (e > E) e = E;
    for (int i = s + threadIdx.x; i < e; i += blockDim.x)
        atomicAdd(&lh[((unsigned)col[i]) >> BSHIFT], 1u);
    __syncthreads();
    for (int i = threadIdx.x; i < nb; i += blockDim.x)
        histM[(size_t)i * NBS + blockIdx.x] = lh[i];
}

// Hierarchical exclusive scan over histM (M = nb*NBS elements), in place.
__launch_bounds__(256)
__global__ void scan1i(unsigned int* __restrict__ data,
                       unsigned int* __restrict__ bsums, int M) {
    __shared__ unsigned int wsum[4];
    const int tid = threadIdx.x;
    const int lane = tid & 63, wv = tid >> 6;
    const int base = blockIdx.x * 1024 + tid * 4;

    unsigned c0 = 0, c1 = 0, c2 = 0, c3 = 0;
    if (base + 3 < M) {
        uint4 c = *reinterpret_cast<const uint4*>(&data[base]);
        c0 = c.x; c1 = c.y; c2 = c.z; c3 = c.w;
    } else {
        if (base     < M) c0 = data[base];
        if (base + 1 < M) c1 = data[base + 1];
        if (base + 2 < M) c2 = data[base + 2];
    }
    unsigned s1 = c0 + c1, s2 = s1 + c2, s3 = s2 + c3;
    unsigned incl = s3;
    #pragma unroll
    for (int off = 1; off < 64; off <<= 1) {
        unsigned v = __shfl_up(incl, off);
        if (lane >= off) incl += v;
    }
    if (lane == 63) wsum[wv] = incl;
    __syncthreads();
    if (tid == 0) {
        unsigned a = 0;
        #pragma unroll
        for (int i = 0; i < 4; ++i) { unsigned t = wsum[i]; wsum[i] = a; a += t; }
        bsums[blockIdx.x] = a;
    }
    __syncthreads();
    unsigned ex = wsum[wv] + (incl - s3);
    if (base + 3 < M) {
        uint4 o; o.x = ex; o.y = ex + c0; o.z = ex + s1; o.w = ex + s2;
        *reinterpret_cast<uint4*>(&data[base]) = o;
    } else {
        if (base     < M) data[base]     = ex;
        if (base + 1 < M) data[base + 1] = ex + c0;
        if (base + 2 < M) data[base + 2] = ex + s1;
    }
}

__global__ void scan2(unsigned int* __restrict__ bsums, int nbq) {
    __shared__ unsigned int lds[1024];
    int tid = threadIdx.x;
    if (tid < nbq) lds[tid] = bsums[tid];
    __syncthreads();
    if (tid == 0) {
        unsigned a = 0;
        for (int i = 0; i < nbq; ++i) { unsigned t = lds[i]; lds[i] = a; a += t; }
    }
    __syncthreads();
    if (tid < nbq) bsums[tid] = lds[tid];
}

__launch_bounds__(256)
__global__ void scan3(unsigned int* __restrict__ data,
                      const unsigned int* __restrict__ bsums, int M) {
    int i = (blockIdx.x * 256 + threadIdx.x) * 4;
    unsigned bs = bsums[blockIdx.x];
    if (i + 3 < M) {
        uint4 v = *reinterpret_cast<const uint4*>(&data[i]);
        v.x += bs; v.y += bs; v.z += bs; v.w += bs;
        *reinterpret_cast<uint4*>(&data[i]) = v;
    } else {
        if (i     < M) data[i]     += bs;
        if (i + 1 < M) data[i + 1] += bs;
        if (i + 2 < M) data[i + 2] += bs;
    }
}

// Group edges by coarse bucket. Base per (bin,block) comes from scanned histM:
// NO global atomics; LDS lpos orders within the block's reservation.
__launch_bounds__(1024)
__global__ void bucket_scatter(const int* __restrict__ row, const int* __restrict__ col,
                               const float* __restrict__ w,
                               const unsigned int* __restrict__ histM,
                               int2* __restrict__ bucketed, int E, int epb, int nb) {
    extern __shared__ unsigned int lds[];
    unsigned int* lbase = lds;
    unsigned int* lpos = lds + nb;
    for (int i = threadIdx.x; i < nb; i += blockDim.x) {
        lbase[i] = histM[(size_t)i * NBS + blockIdx.x];
        lpos[i] = 0;
    }
    __syncthreads();
    int s = blockIdx.x * epb;
    int e = s + epb; if (e > E) e = E;
    for (int i = s + threadIdx.x; i < e; i += blockDim.x) {
        int c = col[i];
        int bk = ((unsigned)c) >> BSHIFT;
        unsigned p = lbase[bk] + atomicAdd(&lpos[bk], 1u);
        bucketed[p] = make_int2(row[i] | ((c & (BNODES - 1)) << 24),
                                __float_as_int(w[i]));
    }
}

// One block per bucket: LDS-compute count+weighted degree (packed u64 LDS
// atomics), write dinv/offs sequentially, place csr entries in the bucket's
// contiguous (L2-resident) region.
__launch_bounds__(256)
__global__ void bucket_finalize(const int2* __restrict__ bucketed,
                                const unsigned int* __restrict__ histM,
                                float* __restrict__ dinv, int* __restrict__ offs,
                                int2* __restrict__ csr, int n, int E, int nb) {
    __shared__ unsigned long long pdeg[BNODES];
    __shared__ unsigned int fineEx[BNODES];
    __shared__ unsigned int lcur[BNODES];
    const int b = blockIdx.x, tid = threadIdx.x;
    const int node0 = b << BSHIFT;
    const int nNodes = min(BNODES, n - node0);
    const unsigned s = histM[(size_t)b * NBS];
    const unsigned e = (b + 1 < nb) ? histM[(size_t)(b + 1) * NBS] : (unsigned)E;

    if (tid < BNODES) { pdeg[tid] = (1ull << 24); lcur[tid] = 0; }  // deg=1 (self-loop)
    __syncthreads();
    for (unsigned i = s + tid; i < e; i += 256) {
        int2 m = bucketed[i];
        unsigned cl = ((unsigned)m.x) >> 24;
        unsigned fx = (unsigned)(__int_as_float(m.y) * 16777216.0f);
        atomicAdd(&pdeg[cl], (1ull << 32) | (unsigned long long)fx);
    }
    __syncthreads();
    if (tid < BNODES) {   // wave 0 only: 64-lane scan
        unsigned long long p = pdeg[tid];
        unsigned cnt = (unsigned)(p >> 32);
        unsigned incl = cnt;
        #pragma unroll
        for (int off = 1; off < 64; off <<= 1) {
            unsigned v = __shfl_up(incl, off);
            if (tid >= off) incl += v;
        }
        fineEx[tid] = incl - cnt;
        if (tid < nNodes) {
            dinv[node0 + tid] = rsqrtf((float)(unsigned)p * 5.9604644775390625e-8f);
            offs[node0 + tid] = (int)(s + incl - cnt);
        }
    }
    __syncthreads();
    for (unsigned i = s + tid; i < e; i += 256) {
        int2 m = bucketed[i];
        unsigned cl = ((unsigned)m.x) >> 24;
        int r = m.x & 0x00FFFFFF;
        unsigned pos = s + fineEx[cl] + atomicAdd(&lcur[cl], 1u);
        csr[pos] = make_int2(r, m.y);   // (srcRow, w bits)
    }
    if (b == 0 && tid == 0) offs[n] = E;
}

// One wave per node, bf16 gathers, 8-way ILP. xbf2 rows pre-scaled by dinv[r];
// per-edge weight = w * dinv[dest].
__launch_bounds__(256)
__global__ void agg_kernel_bf16(const unsigned int* __restrict__ xbf2,
                                const float* __restrict__ dinv,
                                const int* __restrict__ offs, const int2* __restrict__ csr,
                                float* __restrict__ aggOut, int n) {
    int wid = (blockIdx.x * blockDim.x + threadIdx.x) >> 6;
    int lane = threadIdx.x & 63;
    if (wid >= n) return;

    float di = dinv[wid];
    float2 xi = bf2_to_f2(xbf2[(size_t)wid * 64 + lane]);   // = x*dinv already
    float ax0 = di * xi.x, ay0 = di * xi.y;                 // self: di^2 * x
    float ax1 = 0.f,       ay1 = 0.f;

    int s = offs[wid];
    int e = offs[wid + 1];
    int j = s;

    for (; j + 8 <= e; j += 8) {
        int2 m0 = csr[j + 0]; int2 m1 = csr[j + 1];
        int2 m2 = csr[j + 2]; int2 m3 = csr[j + 3];
        int2 m4 = csr[j + 4]; int2 m5 = csr[j + 5];
        int2 m6 = csr[j + 6]; int2 m7 = csr[j + 7];
        unsigned int v0 = xbf2[(size_t)m0.x * 64 + lane];
        unsigned int v1 = xbf2[(size_t)m1.x * 64 + lane];
        unsigned int v2 = xbf2[(size_t)m2.x * 64 + lane];
        unsigned int v3 = xbf2[(size_t)m3.x * 64 + lane];
        unsigned int v4 = xbf2[(size_t)m4.x * 64 + lane];
        unsigned int v5 = xbf2[(size_t)m5.x * 64 + lane];
        unsigned int v6 = xbf2[(size_t)m6.x * 64 + lane];
        unsigned int v7 = xbf2[(size_t)m7.x * 64 + lane];
        float2 f0 = bf2_to_f2(v0); float2 f1 = bf2_to_f2(v1);
        float2 f2 = bf2_to_f2(v2); float2 f3 = bf2_to_f2(v3);
        float2 f4 = bf2_to_f2(v4); float2 f5 = bf2_to_f2(v5);
        float2 f6 = bf2_to_f2(v6); float2 f7 = bf2_to_f2(v7);
        float w0 = __int_as_float(m0.y) * di; float w1 = __int_as_float(m1.y) * di;
        float w2 = __int_as_float(m2.y) * di; float w3 = __int_as_float(m3.y) * di;
        float w4 = __int_as_float(m4.y) * di; float w5 = __int_as_float(m5.y) * di;
        float w6 = __int_as_float(m6.y) * di; float w7 = __int_as_float(m7.y) * di;
        ax0 += w0 * f0.x; ay0 += w0 * f0.y;
        ax1 += w1 * f1.x; ay1 += w1 * f1.y;
        ax0 += w2 * f2.x; ay0 += w2 * f2.y;
        ax1 += w3 * f3.x; ay1 += w3 * f3.y;
        ax0 += w4 * f4.x; ay0 += w4 * f4.y;
        ax1 += w5 * f5.x; ay1 += w5 * f5.y;
        ax0 += w6 * f6.x; ay0 += w6 * f6.y;
        ax1 += w7 * f7.x; ay1 += w7 * f7.y;
    }
    for (; j + 2 <= e; j += 2) {
        int2 m0 = csr[j + 0]; int2 m1 = csr[j + 1];
        unsigned int v0 = xbf2[(size_t)m0.x * 64 + lane];
        unsigned int v1 = xbf2[(size_t)m1.x * 64 + lane];
        float w0 = __int_as_float(m0.y) * di;
        float w1 = __int_as_float(m1.y) * di;
        float2 f0 = bf2_to_f2(v0); float2 f1 = bf2_to_f2(v1);
        ax0 += w0 * f0.x; ay0 += w0 * f0.y;
        ax1 += w1 * f1.x; ay1 += w1 * f1.y;
    }
    for (; j < e; ++j) {
        int2 m = csr[j];
        float2 f = bf2_to_f2(xbf2[(size_t)m.x * 64 + lane]);
        float wn = __int_as_float(m.y) * di;
        ax0 += wn * f.x; ay0 += wn * f.y;
    }

    float2 acc;
    acc.x = ax0 + ax1;
    acc.y = ay0 + ay1;
    *reinterpret_cast<float2*>(&aggOut[(size_t)wid * 128 + lane * 2]) = acc;
}

// MFMA GEMM, in-place on io: io = relu(io @ W + b), bf16x3, no LDS.
__launch_bounds__(256)
__global__ void gemm_mfma2(const unsigned short* __restrict__ Whi,
                           const unsigned short* __restrict__ Wlo,
                           const float* __restrict__ bias,
                           float* __restrict__ io, int n) {
    const int tid = threadIdx.x;
    const int wv = tid >> 6;
    const int l = tid & 63;
    const int row0 = (blockIdx.x * 4 + wv) * 16;
    if (row0 >= n) return;

    const int arow = row0 + (l & 15);
    const int koff = (l >> 4) * 8;
    const bool rok = arow < n;

    short8v ahi[4], alo[4];
    #pragma unroll
    for (int kc = 0; kc < 4; ++kc) {
        float4 p0 = make_float4(0.f, 0.f, 0.f, 0.f);
        float4 p1 = p0;
        if (rok) {
            const float* src = io + (size_t)arow * 128 + kc * 32 + koff;
            p0 = *reinterpret_cast<const float4*>(src);
            p1 = *reinterpret_cast<const float4*>(src + 4);
        }
        float a8[8] = {p0.x, p0.y, p0.z, p0.w, p1.x, p1.y, p1.z, p1.w};
        #pragma unroll
        for (int j = 0; j < 8; ++j) {
            unsigned short h = bf16_rne(a8[j]);
            ahi[kc][j] = (short)h;
            alo[kc][j] = (short)bf16_rne(a8[j] - bf16f(h));
        }
    }

    const int orow = row0 + (l >> 4) * 4;
    const int cbase = l & 15;
    #pragma unroll
    for (int cf = 0; cf < 8; ++cf) {
        int c = cf * 16 + cbase;
        const unsigned short* ph = Whi + c * 128 + koff;
        const unsigned short* pl = Wlo + c * 128 + koff;
        f32x4 acc = {0.f, 0.f, 0.f, 0.f};
        #pragma unroll
        for (int kc = 0; kc < 4; ++kc) {
            short8v bh = *reinterpret_cast<const short8v*>(ph + kc * 32);
            short8v bl = *reinterpret_cast<const short8v*>(pl + kc * 32);
            acc = __builtin_amdgcn_mfma_f32_16x16x32_bf16(ahi[kc], bh, acc, 0, 0, 0);
            acc = __builtin_amdgcn_mfma_f32_16x16x32_bf16(ahi[kc], bl, acc, 0, 0, 0);
            acc = __builtin_amdgcn_mfma_f32_16x16x32_bf16(alo[kc], bh, acc, 0, 0, 0);
        }
        float bb = bias[c];
        #pragma unroll
        for (int j = 0; j < 4; ++j) {
            int r = orow + j;
            if (r < n) io[(size_t)r * 128 + c] = fmaxf(acc[j] + bb, 0.f);
        }
    }
}

static inline size_t align256(size_t v) { return (v + 255) & ~(size_t)255; }

extern "C" void kernel_launch(void* const* d_in, const int* in_sizes, int n_in,
                              void* d_out, int out_size, void* d_ws, size_t ws_size,
                              hipStream_t stream) {
    const float* x = (const float*)d_in[0];
    const int* ei = (const int*)d_in[1];        // harness: integer -> int32
    const float* w = (const float*)d_in[2];
    const float* W = (const float*)d_in[3];
    const float* b = (const float*)d_in[4];
    float* out = (float*)d_out;

    const int N = in_sizes[0] / 128;
    const int E = in_sizes[2];
    const int* row = ei;       // source
    const int* col = ei + E;   // target

    const int nb = (N + BNODES - 1) / BNODES;   // 1563 coarse buckets
    const int M = nb * NBS;                     // histM elements (400k)
    const int nScanB = (M + 1023) / 1024;       // 391

    // Workspace (~39.3 MB, same footprint as R9):
    // [dinv][offs][Whi][Wlo][csr][ UNION: (histM|bsums|bucketed)  vs  xbf2 ]
    char* base = (char*)d_ws;
    size_t off = 0;
    float* dinv = (float*)(base + off);          off = align256(off + (size_t)N * 4);
    int* offs = (int*)(base + off);              off = align256(off + ((size_t)N + 1) * 4);
    unsigned short* Whi = (unsigned short*)(base + off);
    off = align256(off + (size_t)128 * 128 * 2);
    unsigned short* Wlo = (unsigned short*)(base + off);
    off = align256(off + (size_t)128 * 128 * 2);
    int2* csr = (int2*)(base + off);             off = align256(off + (size_t)E * 8);
    // union region
    char* uni = base + off;
    unsigned int* histM = (unsigned int*)uni;                      // M*4 = 1.6 MB
    size_t uoff = align256((size_t)M * 4);
    unsigned int* bsums = (unsigned int*)(uni + uoff);
    uoff = align256(uoff + (size_t)nScanB * 4);
    int2* bucketed = (int2*)(uni + uoff);                          // E*8 = 12.8 MB
    unsigned int* xbf2 = (unsigned int*)uni;                       // N*256 = 25.6 MB

    const int epb = (E + NBS - 1) / NBS;       // 6250
    const int nx8 = (N * 128) / 8;

    wsplit_kernel<<<64, 256, 0, stream>>>(W, Whi, Wlo);
    coarse_hist<<<NBS, 1024, nb * 4, stream>>>(col, histM, E, epb, nb);
    scan1i<<<nScanB, 256, 0, stream>>>(histM, bsums, M);
    scan2<<<1, 1024, 0, stream>>>(bsums, nScanB);
    scan3<<<nScanB, 256, 0, stream>>>(histM, bsums, M);
    bucket_scatter<<<NBS, 1024, 2 * nb * 4, stream>>>(row, col, w, histM, bucketed,
                                                      E, epb, nb);
    bucket_finalize<<<nb, 256, 0, stream>>>(bucketed, histM, dinv, offs, csr, N, E, nb);
    cvt_kernel<<<2048, 256, 0, stream>>>(x, dinv, xbf2, nx8);  // overwrites union (dead)
    agg_kernel_bf16<<<(N + 3) / 4, 256, 0, stream>>>(xbf2, dinv, offs, csr, out, N);
    gemm_mfma2<<<(N + 63) / 64, 256, 0, stream>>>(Whi, Wlo, b, out, N);
}